// Round 1
// baseline (492.250 us; speedup 1.0000x reference)
//
#include <hip/hip_runtime.h>
#include <math.h>

// Problem constants: M=512 (gt boxes), N=1024 (ctx boxes), G=16 groups, D=64, C=1024 feat.
// Workspace map (float offsets). Peak live = 35,127,296 floats = 140.5 MB.
//   q       : [0, 524288)            (M x 1024)
//   k       : [524288, 1572864)      (N x 1024)
//   scores  : [1572864, 9961472)     (G,M,N)  -> becomes w1 in-place after softmax
//   scoresT : [9961472, 18350080)    (G,N,M)  -> becomes w2 in-place after softmax
//   bias_gt : [18350080, 26738688)   (G,M,N)  log-clipped position logits
//   bias_ctx: [26738688, 35127296)   (G,N,M)
//   vT1     : [0, 1048576)           (G,64,N) aliases q/k region (dead after scores GEMMs)
//   vT2     : [1048576, 1572864)     (G,64,M)

#define M_GT 512
#define N_CTX 1024
#define NFEAT 1024
#define NG 16

// ---------------------------------------------------------------------------
// Batched NT GEMM: C[b][i][j] = alpha * sum_k A[b][i][k]*B[b][j][k] + bias[b][j]
// Tile 64x64, BK=16, 256 threads, 4x4 microtile. Requires M,N %64==0, K %16==0.
// ---------------------------------------------------------------------------
__global__ __launch_bounds__(256) void gemm_nt_64x64(
    const float* __restrict__ A, const float* __restrict__ B,
    float* __restrict__ C, const float* __restrict__ bias,
    int K, int lda, int ldb, int ldc,
    long long sA, long long sB, long long sC, long long sBias, float alpha)
{
    const int b = blockIdx.z;
    A += (long long)b * sA;
    B += (long long)b * sB;
    C += (long long)b * sC;
    const int bm = blockIdx.x * 64;
    const int bn = blockIdx.y * 64;

    __shared__ float As[16][68];   // [k][m], pad 4 keeps float4 alignment, 2-way banks (free)
    __shared__ float Bs[16][68];   // [k][n]

    const int tid = threadIdx.x;
    const int ty = tid >> 4;        // 0..15 -> C rows ty*4..+3
    const int tx = tid & 15;        // 0..15 -> C cols tx*4..+3
    const int lr = tid >> 2;        // 0..63 loader row
    const int lk = (tid & 3) << 2;  // 0,4,8,12 loader k (float4)

    const float* Aptr = A + (long long)(bm + lr) * lda + lk;
    const float* Bptr = B + (long long)(bn + lr) * ldb + lk;

    float acc[4][4] = {{0.f,0.f,0.f,0.f},{0.f,0.f,0.f,0.f},{0.f,0.f,0.f,0.f},{0.f,0.f,0.f,0.f}};

    for (int k0 = 0; k0 < K; k0 += 16) {
        float4 av = *(const float4*)(Aptr + k0);
        float4 bv = *(const float4*)(Bptr + k0);
        __syncthreads();
        As[lk+0][lr] = av.x; As[lk+1][lr] = av.y; As[lk+2][lr] = av.z; As[lk+3][lr] = av.w;
        Bs[lk+0][lr] = bv.x; Bs[lk+1][lr] = bv.y; Bs[lk+2][lr] = bv.z; Bs[lk+3][lr] = bv.w;
        __syncthreads();
        #pragma unroll
        for (int kk = 0; kk < 16; ++kk) {
            float4 a4 = *(const float4*)&As[kk][ty << 2];
            float4 b4 = *(const float4*)&Bs[kk][tx << 2];
            float ar[4] = {a4.x, a4.y, a4.z, a4.w};
            float br[4] = {b4.x, b4.y, b4.z, b4.w};
            #pragma unroll
            for (int i = 0; i < 4; ++i)
                #pragma unroll
                for (int j = 0; j < 4; ++j)
                    acc[i][j] = fmaf(ar[i], br[j], acc[i][j]);
        }
    }

    float4 bias4 = make_float4(0.f, 0.f, 0.f, 0.f);
    if (bias) bias4 = *(const float4*)(bias + (long long)b * sBias + bn + (tx << 2));

    #pragma unroll
    for (int i = 0; i < 4; ++i) {
        float4 o;
        o.x = fmaf(alpha, acc[i][0], bias4.x);
        o.y = fmaf(alpha, acc[i][1], bias4.y);
        o.z = fmaf(alpha, acc[i][2], bias4.z);
        o.w = fmaf(alpha, acc[i][3], bias4.w);
        *(float4*)(C + (long long)(bm + (ty << 2) + i) * ldc + bn + (tx << 2)) = o;
    }
}

// ---------------------------------------------------------------------------
// Position-embedding bias: out[g, i, j] = log(clip(relu(pe(i,j)) . w_pos[g] + b_pos[g], 1e-6))
// boxA supplies rows (and the bw/bh denominators), boxB supplies cols.
// One thread per (i,j) pair. ncols = 1<<shift.
// ---------------------------------------------------------------------------
__global__ __launch_bounds__(256) void pos_bias_kernel(
    const float* __restrict__ boxA, const float* __restrict__ boxB,
    const float* __restrict__ w_pos, const float* __restrict__ b_pos,
    float* __restrict__ out, int nrows, int shift)
{
    __shared__ float wt[64 * 16];            // wt[i*16+g] = w_pos[g*64+i]
    const int tid = threadIdx.x;
    for (int t = tid; t < 1024; t += 256) {
        int g = t >> 6, i = t & 63;
        wt[i * 16 + g] = w_pos[t];
    }
    __syncthreads();

    const int ncols = 1 << shift;
    const long long idx = (long long)blockIdx.x * 256 + tid;
    const int i = (int)(idx >> shift);
    const int j = (int)(idx & (ncols - 1));

    float4 ba = *(const float4*)(boxA + i * 4);
    float4 bb = *(const float4*)(boxB + j * 4);
    float bw = ba.z - ba.x + 1.f, bh = ba.w - ba.y + 1.f;
    float cx = 0.5f * (ba.x + ba.z), cy = 0.5f * (ba.y + ba.w);
    float cbw = bb.z - bb.x + 1.f, cbh = bb.w - bb.y + 1.f;
    float ccx = 0.5f * (bb.x + bb.z), ccy = 0.5f * (bb.y + bb.w);

    float pos4[4];
    pos4[0] = logf(fmaxf(fabsf((cx - ccx) / bw), 1e-3f));
    pos4[1] = logf(fmaxf(fabsf((cy - ccy) / bh), 1e-3f));
    pos4[2] = logf(cbw / bw);
    pos4[3] = logf(cbh / bh);

    // 1000^(-f/8), f=0..7
    const float inv_dim[8] = {
        1.0f, 0.42169650342f, 0.17782794100f, 0.07498942093f,
        0.03162277660f, 0.01333521432f, 0.00562341325f, 0.00237137371f };

    float acc[16];
    #pragma unroll
    for (int g = 0; g < 16; ++g) acc[g] = b_pos[g];

    #pragma unroll
    for (int p = 0; p < 4; ++p) {
        float base = 100.f * pos4[p];
        #pragma unroll
        for (int f = 0; f < 8; ++f) {
            float t = base * inv_dim[f];
            float s, c;
            __sincosf(t, &s, &c);
            float rs = fmaxf(s, 0.f);
            float rc = fmaxf(c, 0.f);
            const float4* w4s = (const float4*)&wt[(p * 16 + f) * 16];
            const float4* w4c = (const float4*)&wt[(p * 16 + 8 + f) * 16];
            #pragma unroll
            for (int q = 0; q < 4; ++q) {
                float4 ws4 = w4s[q];
                float4 wc4 = w4c[q];
                acc[4*q+0] = fmaf(rs, ws4.x, acc[4*q+0]);
                acc[4*q+1] = fmaf(rs, ws4.y, acc[4*q+1]);
                acc[4*q+2] = fmaf(rs, ws4.z, acc[4*q+2]);
                acc[4*q+3] = fmaf(rs, ws4.w, acc[4*q+3]);
                acc[4*q+0] = fmaf(rc, wc4.x, acc[4*q+0]);
                acc[4*q+1] = fmaf(rc, wc4.y, acc[4*q+1]);
                acc[4*q+2] = fmaf(rc, wc4.z, acc[4*q+2]);
                acc[4*q+3] = fmaf(rc, wc4.w, acc[4*q+3]);
            }
        }
    }

    const long long plane = (long long)nrows << shift;
    #pragma unroll
    for (int g = 0; g < 16; ++g)
        out[(long long)g * plane + idx] = logf(fmaxf(acc[g], 1e-6f));
}

// ---------------------------------------------------------------------------
// In-place row softmax of (data + bias). Row length = CNT*256. One block/row.
// ---------------------------------------------------------------------------
template <int CNT>
__global__ __launch_bounds__(256) void softmax_rows(
    float* __restrict__ data, const float* __restrict__ bias)
{
    const int L = CNT * 256;
    const long long row = blockIdx.x;
    float* d = data + row * (long long)L;
    const float* bp = bias + row * (long long)L;
    const int tid = threadIdx.x;

    float v[CNT];
    float mx = -1e30f;
    #pragma unroll
    for (int c = 0; c < CNT; ++c) {
        v[c] = d[tid + 256 * c] + bp[tid + 256 * c];
        mx = fmaxf(mx, v[c]);
    }
    #pragma unroll
    for (int off = 32; off >= 1; off >>= 1)
        mx = fmaxf(mx, __shfl_xor(mx, off, 64));

    __shared__ float redm[4], reds[4];
    if ((tid & 63) == 0) redm[tid >> 6] = mx;
    __syncthreads();
    mx = fmaxf(fmaxf(redm[0], redm[1]), fmaxf(redm[2], redm[3]));

    float sum = 0.f;
    #pragma unroll
    for (int c = 0; c < CNT; ++c) { v[c] = __expf(v[c] - mx); sum += v[c]; }
    #pragma unroll
    for (int off = 32; off >= 1; off >>= 1)
        sum += __shfl_xor(sum, off, 64);
    if ((tid & 63) == 0) reds[tid >> 6] = sum;
    __syncthreads();
    sum = reds[0] + reds[1] + reds[2] + reds[3];

    float inv = 1.0f / sum;
    #pragma unroll
    for (int c = 0; c < CNT; ++c) d[tid + 256 * c] = v[c] * inv;
}

// ---------------------------------------------------------------------------
extern "C" void kernel_launch(void* const* d_in, const int* in_sizes, int n_in,
                              void* d_out, int out_size, void* d_ws, size_t ws_size,
                              hipStream_t stream)
{
    const float* feat     = (const float*)d_in[0];   // (512,1024)
    const float* ctx_feat = (const float*)d_in[1];   // (1024,1024)
    const float* box      = (const float*)d_in[2];   // (512,4)
    const float* ctx_box  = (const float*)d_in[3];   // (1024,4)
    const float* w_fc_gt  = (const float*)d_in[4];
    const float* b_fc_gt  = (const float*)d_in[5];
    const float* w_fc_ctx = (const float*)d_in[6];
    const float* b_fc_ctx = (const float*)d_in[7];
    const float* w_pos_gt = (const float*)d_in[8];
    const float* b_pos_gt = (const float*)d_in[9];
    const float* w_pos_ctx= (const float*)d_in[10];
    const float* b_pos_ctx= (const float*)d_in[11];
    const float* w_conv   = (const float*)d_in[12];  // (16,64,1024)
    const float* b_conv   = (const float*)d_in[13];

    float* ws       = (float*)d_ws;
    float* q        = ws;                  // 512*1024
    float* kbuf     = ws + 524288LL;       // 1024*1024
    float* scores   = ws + 1572864LL;      // (G,M,N)
    float* scoresT  = ws + 9961472LL;      // (G,N,M)
    float* bias_gt  = ws + 18350080LL;     // (G,M,N)
    float* bias_ctx = ws + 26738688LL;     // (G,N,M)
    float* vT1      = ws;                  // (G,64,N) aliases q/k (dead by then)
    float* vT2      = ws + 1048576LL;      // (G,64,M)

    float* out_gt  = (float*)d_out;            // (512,1024)
    float* out_ctx = (float*)d_out + 524288LL; // (1024,1024)

    // 1) position bias logits (both directions)
    hipLaunchKernelGGL(pos_bias_kernel, dim3(2048), dim3(256), 0, stream,
                       box, ctx_box, w_pos_gt, b_pos_gt, bias_gt, M_GT, 10);
    hipLaunchKernelGGL(pos_bias_kernel, dim3(2048), dim3(256), 0, stream,
                       ctx_box, box, w_pos_ctx, b_pos_ctx, bias_ctx, N_CTX, 9);

    // 2) q = feat @ w_fc_gt^T + b ; k = ctx_feat @ w_fc_ctx^T + b
    hipLaunchKernelGGL(gemm_nt_64x64, dim3(8, 16, 1), dim3(256), 0, stream,
                       feat, w_fc_gt, q, b_fc_gt, 1024, 1024, 1024, 1024,
                       0LL, 0LL, 0LL, 0LL, 1.0f);
    hipLaunchKernelGGL(gemm_nt_64x64, dim3(16, 16, 1), dim3(256), 0, stream,
                       ctx_feat, w_fc_ctx, kbuf, b_fc_ctx, 1024, 1024, 1024, 1024,
                       0LL, 0LL, 0LL, 0LL, 1.0f);

    // 3) scores[g] = q_g @ k_g^T / 8 ; scoresT[g] = k_g @ q_g^T / 8
    hipLaunchKernelGGL(gemm_nt_64x64, dim3(8, 16, NG), dim3(256), 0, stream,
                       q, kbuf, scores, (const float*)nullptr, 64, 1024, 1024, 1024,
                       64LL, 64LL, 524288LL, 0LL, 0.125f);
    hipLaunchKernelGGL(gemm_nt_64x64, dim3(16, 8, NG), dim3(256), 0, stream,
                       kbuf, q, scoresT, (const float*)nullptr, 64, 1024, 1024, 512,
                       64LL, 64LL, 524288LL, 0LL, 0.125f);

    // 4) softmax over last axis (in-place, +bias)
    hipLaunchKernelGGL((softmax_rows<4>), dim3(NG * M_GT), dim3(256), 0, stream,
                       scores, bias_gt);
    hipLaunchKernelGGL((softmax_rows<2>), dim3(NG * N_CTX), dim3(256), 0, stream,
                       scoresT, bias_ctx);

    // 5) vT1[g] = w_conv[g] @ ctx_feat^T ; vT2[g] = w_conv[g] @ feat^T
    hipLaunchKernelGGL(gemm_nt_64x64, dim3(1, 16, NG), dim3(256), 0, stream,
                       w_conv, ctx_feat, vT1, (const float*)nullptr, 1024, 1024, 1024, 1024,
                       65536LL, 0LL, 65536LL, 0LL, 1.0f);
    hipLaunchKernelGGL(gemm_nt_64x64, dim3(1, 8, NG), dim3(256), 0, stream,
                       w_conv, feat, vT2, (const float*)nullptr, 1024, 1024, 1024, 512,
                       65536LL, 0LL, 32768LL, 0LL, 1.0f);

    // 6) out_gt[:, g*64+o] = w1[g] @ vT1[g]^T + b_conv[g*64+o]
    hipLaunchKernelGGL(gemm_nt_64x64, dim3(8, 1, NG), dim3(256), 0, stream,
                       scores, vT1, out_gt, b_conv, 1024, 1024, 1024, 1024,
                       524288LL, 65536LL, 64LL, 64LL, 1.0f);
    //    out_ctx[:, g*64+o] = w2[g] @ vT2[g]^T + b_conv[g*64+o]
    hipLaunchKernelGGL(gemm_nt_64x64, dim3(16, 1, NG), dim3(256), 0, stream,
                       scoresT, vT2, out_ctx, b_conv, 512, 512, 512, 1024,
                       524288LL, 32768LL, 64LL, 64LL, 1.0f);
}

// Round 2
// 284.135 us; speedup vs baseline: 1.7325x; 1.7325x over previous
//
#include <hip/hip_runtime.h>
#include <math.h>

// M=512, N=1024, G=16, D=64, C=1024.
// All heavy GEMMs run as bf16 MFMA (16x16x32), fp32 accumulate.
//
// Workspace (float offsets), peak ~147 MB:
//   pool A (shorts over floats [0,1572864)):
//     feat_bf  @0        (524288 s)
//     q_bf     @524288   (524288 s)
//     k_bf     @1048576  (1048576 s)
//     vT2_bf   @2097152  (524288 s)
//   scores  : [1572864, 9961472)   fp32 (G,M,N) -> logits -> softmax packs bf16 in place
//     (wfcgt_bf/wfcctx_bf live in the first 2M shorts of this region until proj GEMMs done)
//   scoresT : [9961472, 18350080)  fp32 (G,N,M)
//   bias_gt : [18350080, 26738688) fp32 (G,M,N) position logits
//   bias_ctx: [26738688, 35127296) fp32 (G,N,M)
//   tail (shorts from float 35127296): ctx_bf (1048576 s), wconv_bf (1048576 s), vT1_bf (1048576 s)

#define M_GT 512
#define N_CTX 1024
#define NG 16

typedef __attribute__((ext_vector_type(8))) short short8;   // 8 bf16 = 4 VGPRs
typedef __attribute__((ext_vector_type(4))) float floatx4;

__device__ inline unsigned short f32_bf16_rne(float x) {
    union { float f; unsigned u; } v; v.f = x;
    unsigned u = v.u;
    return (unsigned short)((u + 0x7fffu + ((u >> 16) & 1u)) >> 16);
}

// ---------------------------------------------------------------------------
// fp32 -> bf16 cast for 5 tensors in one launch. blockIdx.y selects tensor.
// ---------------------------------------------------------------------------
__global__ __launch_bounds__(256) void conv5_f32_bf16(
    const float* s0, unsigned short* d0, int n0,
    const float* s1, unsigned short* d1, int n1,
    const float* s2, unsigned short* d2, int n2,
    const float* s3, unsigned short* d3, int n3,
    const float* s4, unsigned short* d4, int n4)
{
    const float* s; unsigned short* d; int n;
    switch (blockIdx.y) {
        case 0: s = s0; d = d0; n = n0; break;
        case 1: s = s1; d = d1; n = n1; break;
        case 2: s = s2; d = d2; n = n2; break;
        case 3: s = s3; d = d3; n = n3; break;
        default: s = s4; d = d4; n = n4; break;
    }
    int idx = (blockIdx.x * 256 + threadIdx.x) * 4;
    if (idx < n) {
        float4 v = *(const float4*)(s + idx);
        ushort4 o;
        o.x = f32_bf16_rne(v.x); o.y = f32_bf16_rne(v.y);
        o.z = f32_bf16_rne(v.z); o.w = f32_bf16_rne(v.w);
        *(ushort4*)(d + idx) = o;
    }
}

// ---------------------------------------------------------------------------
// Batched NT bf16 MFMA GEMM, 64x64 tile, 4 waves, each wave a 32x32 quadrant.
// C[b][i][j] = alpha * sum_k A[b][i][k]*B[b][j][k] + biasvec[b][j] + addmat[b][i][j]
// Requires: M,N multiples of 64; K multiple of 32; lda/ldb multiples of 8.
// ---------------------------------------------------------------------------
template <bool OUT_BF16>
__global__ __launch_bounds__(256) void gemm_bf16_nt(
    const unsigned short* __restrict__ A, const unsigned short* __restrict__ B,
    void* __restrict__ Cv, const float* __restrict__ biasvec,
    const float* __restrict__ addmat,
    int K, int lda, int ldb, int ldc, int ldadd,
    long long sA, long long sB, long long sC, long long sBias, long long sAdd,
    float alpha)
{
    const int b = blockIdx.z;
    A += (long long)b * sA;
    B += (long long)b * sB;
    const int bm = blockIdx.x * 64;
    const int bn = blockIdx.y * 64;

    // row stride 40 shorts = 80 B: keeps 16B alignment, 2-way banks only (free)
    __shared__ __align__(16) unsigned short As[64 * 40];
    __shared__ __align__(16) unsigned short Bs[64 * 40];

    const int tid = threadIdx.x;
    const int lr = tid >> 2;          // loader row 0..63
    const int lk = (tid & 3) * 8;     // loader k: 0,8,16,24 (x8 bf16 = 16B)
    const int lane = tid & 63;
    const int wave = tid >> 6;
    const int qr = (wave >> 1) * 32;  // quadrant row of this wave
    const int qc = (wave & 1) * 32;
    const int m = lane & 15;
    const int quad = lane >> 4;

    const unsigned short* Ap = A + (long long)(bm + lr) * lda + lk;
    const unsigned short* Bp = B + (long long)(bn + lr) * ldb + lk;

    unsigned short* AsW = &As[lr * 40 + lk];
    unsigned short* BsW = &Bs[lr * 40 + lk];
    const unsigned short* a0p = &As[(qr + m) * 40 + quad * 8];
    const unsigned short* a1p = a0p + 16 * 40;
    const unsigned short* b0p = &Bs[(qc + m) * 40 + quad * 8];
    const unsigned short* b1p = b0p + 16 * 40;

    floatx4 acc00 = {0.f,0.f,0.f,0.f}, acc01 = {0.f,0.f,0.f,0.f};
    floatx4 acc10 = {0.f,0.f,0.f,0.f}, acc11 = {0.f,0.f,0.f,0.f};

    for (int k0 = 0; k0 < K; k0 += 32) {
        int4 av = *(const int4*)(Ap + k0);
        int4 bv = *(const int4*)(Bp + k0);
        __syncthreads();
        *(int4*)AsW = av;
        *(int4*)BsW = bv;
        __syncthreads();
        short8 a0 = *(const short8*)a0p;
        short8 a1 = *(const short8*)a1p;
        short8 b0 = *(const short8*)b0p;
        short8 b1 = *(const short8*)b1p;
        acc00 = __builtin_amdgcn_mfma_f32_16x16x32_bf16(a0, b0, acc00, 0, 0, 0);
        acc01 = __builtin_amdgcn_mfma_f32_16x16x32_bf16(a0, b1, acc01, 0, 0, 0);
        acc10 = __builtin_amdgcn_mfma_f32_16x16x32_bf16(a1, b0, acc10, 0, 0, 0);
        acc11 = __builtin_amdgcn_mfma_f32_16x16x32_bf16(a1, b1, acc11, 0, 0, 0);
    }

    // column bias for the two 16-wide column tiles of this quadrant
    float bias0 = 0.f, bias1 = 0.f;
    if (biasvec) {
        bias0 = biasvec[b * sBias + bn + qc + m];
        bias1 = biasvec[b * sBias + bn + qc + 16 + m];
    }

    const floatx4 accs[2][2] = { {acc00, acc01}, {acc10, acc11} };
    #pragma unroll
    for (int i = 0; i < 2; ++i) {
        #pragma unroll
        for (int r = 0; r < 4; ++r) {
            const int grow = bm + qr + i * 16 + quad * 4 + r;
            #pragma unroll
            for (int j = 0; j < 2; ++j) {
                const int gcol = bn + qc + j * 16 + m;
                float val = alpha * accs[i][j][r] + (j ? bias1 : bias0);
                if (addmat)
                    val += addmat[b * sAdd + (long long)grow * ldadd + gcol];
                const long long ci = (long long)grow * ldc + gcol;
                if (OUT_BF16)
                    ((unsigned short*)Cv)[b * sC + ci] = f32_bf16_rne(val);
                else
                    ((float*)Cv)[b * sC + ci] = val;
            }
        }
    }
}

// ---------------------------------------------------------------------------
// Position bias logits: out[g,i,j] = log(max(relu(pe(i,j)).w_pos[g]+b_pos[g],1e-6))
// ---------------------------------------------------------------------------
__global__ __launch_bounds__(256) void pos_bias_kernel(
    const float* __restrict__ boxA, const float* __restrict__ boxB,
    const float* __restrict__ w_pos, const float* __restrict__ b_pos,
    float* __restrict__ out, int nrows, int shift)
{
    __shared__ float wt[64 * 16];            // wt[i*16+g] = w_pos[g*64+i]
    const int tid = threadIdx.x;
    for (int t = tid; t < 1024; t += 256) {
        int g = t >> 6, i = t & 63;
        wt[i * 16 + g] = w_pos[t];
    }
    __syncthreads();

    const int ncols = 1 << shift;
    const long long idx = (long long)blockIdx.x * 256 + tid;
    const int i = (int)(idx >> shift);
    const int j = (int)(idx & (ncols - 1));

    float4 ba = *(const float4*)(boxA + i * 4);
    float4 bb = *(const float4*)(boxB + j * 4);
    float bw = ba.z - ba.x + 1.f, bh = ba.w - ba.y + 1.f;
    float cx = 0.5f * (ba.x + ba.z), cy = 0.5f * (ba.y + ba.w);
    float cbw = bb.z - bb.x + 1.f, cbh = bb.w - bb.y + 1.f;
    float ccx = 0.5f * (bb.x + bb.z), ccy = 0.5f * (bb.y + bb.w);

    float pos4[4];
    pos4[0] = logf(fmaxf(fabsf((cx - ccx) / bw), 1e-3f));
    pos4[1] = logf(fmaxf(fabsf((cy - ccy) / bh), 1e-3f));
    pos4[2] = logf(cbw / bw);
    pos4[3] = logf(cbh / bh);

    const float inv_dim[8] = {
        1.0f, 0.42169650342f, 0.17782794100f, 0.07498942093f,
        0.03162277660f, 0.01333521432f, 0.00562341325f, 0.00237137371f };

    float acc[16];
    #pragma unroll
    for (int g = 0; g < 16; ++g) acc[g] = b_pos[g];

    #pragma unroll
    for (int p = 0; p < 4; ++p) {
        float base = 100.f * pos4[p];
        #pragma unroll
        for (int f = 0; f < 8; ++f) {
            float t = base * inv_dim[f];
            float s, c;
            __sincosf(t, &s, &c);
            float rs = fmaxf(s, 0.f);
            float rc = fmaxf(c, 0.f);
            const float4* w4s = (const float4*)&wt[(p * 16 + f) * 16];
            const float4* w4c = (const float4*)&wt[(p * 16 + 8 + f) * 16];
            #pragma unroll
            for (int q = 0; q < 4; ++q) {
                float4 ws4 = w4s[q];
                float4 wc4 = w4c[q];
                acc[4*q+0] = fmaf(rs, ws4.x, acc[4*q+0]);
                acc[4*q+1] = fmaf(rs, ws4.y, acc[4*q+1]);
                acc[4*q+2] = fmaf(rs, ws4.z, acc[4*q+2]);
                acc[4*q+3] = fmaf(rs, ws4.w, acc[4*q+3]);
                acc[4*q+0] = fmaf(rc, wc4.x, acc[4*q+0]);
                acc[4*q+1] = fmaf(rc, wc4.y, acc[4*q+1]);
                acc[4*q+2] = fmaf(rc, wc4.z, acc[4*q+2]);
                acc[4*q+3] = fmaf(rc, wc4.w, acc[4*q+3]);
            }
        }
    }

    const long long plane = (long long)nrows << shift;
    #pragma unroll
    for (int g = 0; g < 16; ++g)
        out[(long long)g * plane + idx] = logf(fmaxf(acc[g], 1e-6f));
}

// ---------------------------------------------------------------------------
// Row softmax of fp32 logits; writes bf16 in place (each row's bf16 output
// fits inside its own fp32 row footprint; barrier separates reads from writes).
// ---------------------------------------------------------------------------
template <int CNT>
__global__ __launch_bounds__(256) void softmax_rows_bf16(float* __restrict__ data)
{
    const int L = CNT * 256;
    float* d = data + (long long)blockIdx.x * L;
    const int tid = threadIdx.x;

    float v[CNT];
    float mx = -1e30f;
    #pragma unroll
    for (int c = 0; c < CNT; ++c) {
        v[c] = d[tid + 256 * c];
        mx = fmaxf(mx, v[c]);
    }
    #pragma unroll
    for (int off = 32; off >= 1; off >>= 1)
        mx = fmaxf(mx, __shfl_xor(mx, off, 64));

    __shared__ float redm[4], reds[4];
    if ((tid & 63) == 0) redm[tid >> 6] = mx;
    __syncthreads();
    mx = fmaxf(fmaxf(redm[0], redm[1]), fmaxf(redm[2], redm[3]));

    float sum = 0.f;
    #pragma unroll
    for (int c = 0; c < CNT; ++c) { v[c] = __expf(v[c] - mx); sum += v[c]; }
    #pragma unroll
    for (int off = 32; off >= 1; off >>= 1)
        sum += __shfl_xor(sum, off, 64);
    if ((tid & 63) == 0) reds[tid >> 6] = sum;
    __syncthreads();   // also guarantees all fp32 reads done before bf16 writes
    sum = reds[0] + reds[1] + reds[2] + reds[3];

    float inv = 1.0f / sum;
    unsigned short* o = (unsigned short*)d;
    #pragma unroll
    for (int c = 0; c < CNT; ++c)
        o[tid + 256 * c] = f32_bf16_rne(v[c] * inv);
}

// ---------------------------------------------------------------------------
extern "C" void kernel_launch(void* const* d_in, const int* in_sizes, int n_in,
                              void* d_out, int out_size, void* d_ws, size_t ws_size,
                              hipStream_t stream)
{
    const float* feat     = (const float*)d_in[0];
    const float* ctx_feat = (const float*)d_in[1];
    const float* box      = (const float*)d_in[2];
    const float* ctx_box  = (const float*)d_in[3];
    const float* w_fc_gt  = (const float*)d_in[4];
    const float* b_fc_gt  = (const float*)d_in[5];
    const float* w_fc_ctx = (const float*)d_in[6];
    const float* b_fc_ctx = (const float*)d_in[7];
    const float* w_pos_gt = (const float*)d_in[8];
    const float* b_pos_gt = (const float*)d_in[9];
    const float* w_pos_ctx= (const float*)d_in[10];
    const float* b_pos_ctx= (const float*)d_in[11];
    const float* w_conv   = (const float*)d_in[12];
    const float* b_conv   = (const float*)d_in[13];

    float* ws = (float*)d_ws;
    // fp32 regions
    float* scores   = ws + 1572864LL;   // (G,M,N) logits -> bf16 w1 packed in place
    float* scoresT  = ws + 9961472LL;   // (G,N,M) logits -> bf16 w2 packed in place
    float* bias_gt  = ws + 18350080LL;
    float* bias_ctx = ws + 26738688LL;
    // bf16 pool A over floats [0, 1572864)
    unsigned short* pool0   = (unsigned short*)ws;
    unsigned short* feat_bf = pool0;                 // 524288
    unsigned short* q_bf    = pool0 + 524288LL;      // 524288
    unsigned short* k_bf    = pool0 + 1048576LL;     // 1048576
    unsigned short* vT2_bf  = pool0 + 2097152LL;     // 524288
    // transient: fc weights live in scores region until proj GEMMs finish
    unsigned short* wfcgt_bf  = (unsigned short*)scores;
    unsigned short* wfcctx_bf = (unsigned short*)scores + 1048576LL;
    // tail bf16 pool
    unsigned short* pool1    = (unsigned short*)(ws + 35127296LL);
    unsigned short* ctx_bf   = pool1;                // 1048576
    unsigned short* wconv_bf = pool1 + 1048576LL;    // 1048576
    unsigned short* vT1_bf   = pool1 + 2097152LL;    // 1048576

    float* out_gt  = (float*)d_out;
    float* out_ctx = (float*)d_out + 524288LL;

    // 1) casts
    hipLaunchKernelGGL(conv5_f32_bf16, dim3(1024, 5), dim3(256), 0, stream,
                       feat, feat_bf, 524288,
                       ctx_feat, ctx_bf, 1048576,
                       w_fc_gt, wfcgt_bf, 1048576,
                       w_fc_ctx, wfcctx_bf, 1048576,
                       w_conv, wconv_bf, 1048576);

    // 2) position bias logits
    hipLaunchKernelGGL(pos_bias_kernel, dim3(2048), dim3(256), 0, stream,
                       box, ctx_box, w_pos_gt, b_pos_gt, bias_gt, M_GT, 10);
    hipLaunchKernelGGL(pos_bias_kernel, dim3(2048), dim3(256), 0, stream,
                       ctx_box, box, w_pos_ctx, b_pos_ctx, bias_ctx, N_CTX, 9);

    // 3) projections -> bf16
    hipLaunchKernelGGL((gemm_bf16_nt<true>), dim3(8, 16, 1), dim3(256), 0, stream,
                       feat_bf, wfcgt_bf, (void*)q_bf, b_fc_gt, (const float*)nullptr,
                       1024, 1024, 1024, 1024, 0,
                       0LL, 0LL, 0LL, 0LL, 0LL, 1.0f);
    hipLaunchKernelGGL((gemm_bf16_nt<true>), dim3(16, 16, 1), dim3(256), 0, stream,
                       ctx_bf, wfcctx_bf, (void*)k_bf, b_fc_ctx, (const float*)nullptr,
                       1024, 1024, 1024, 1024, 0,
                       0LL, 0LL, 0LL, 0LL, 0LL, 1.0f);

    // 4) scores + position bias -> fp32 logits (bias fused via addmat)
    hipLaunchKernelGGL((gemm_bf16_nt<false>), dim3(8, 16, NG), dim3(256), 0, stream,
                       q_bf, k_bf, (void*)scores, (const float*)nullptr, bias_gt,
                       64, 1024, 1024, 1024, 1024,
                       64LL, 64LL, 524288LL, 0LL, 524288LL, 0.125f);
    hipLaunchKernelGGL((gemm_bf16_nt<false>), dim3(16, 8, NG), dim3(256), 0, stream,
                       k_bf, q_bf, (void*)scoresT, (const float*)nullptr, bias_ctx,
                       64, 1024, 1024, 512, 512,
                       64LL, 64LL, 524288LL, 0LL, 524288LL, 0.125f);

    // 5) softmax -> bf16 packed in place
    hipLaunchKernelGGL((softmax_rows_bf16<4>), dim3(NG * M_GT), dim3(256), 0, stream, scores);
    hipLaunchKernelGGL((softmax_rows_bf16<2>), dim3(NG * N_CTX), dim3(256), 0, stream, scoresT);

    // 6) v projections: vT1[g]=w_conv[g]@ctx^T, vT2[g]=w_conv[g]@feat^T -> bf16
    hipLaunchKernelGGL((gemm_bf16_nt<true>), dim3(1, 16, NG), dim3(256), 0, stream,
                       wconv_bf, ctx_bf, (void*)vT1_bf, (const float*)nullptr, (const float*)nullptr,
                       1024, 1024, 1024, 1024, 0,
                       65536LL, 0LL, 65536LL, 0LL, 0LL, 1.0f);
    hipLaunchKernelGGL((gemm_bf16_nt<true>), dim3(1, 8, NG), dim3(256), 0, stream,
                       wconv_bf, feat_bf, (void*)vT2_bf, (const float*)nullptr, (const float*)nullptr,
                       1024, 1024, 1024, 512, 0,
                       65536LL, 0LL, 32768LL, 0LL, 0LL, 1.0f);

    // 7) outputs: out = softmaxW @ vT^T + b_conv
    //    w1 packed bf16 inside scores fp32 rows: lda = 2048 shorts, sA = 1048576 shorts
    hipLaunchKernelGGL((gemm_bf16_nt<false>), dim3(8, 1, NG), dim3(256), 0, stream,
                       (const unsigned short*)scores, vT1_bf, (void*)out_gt, b_conv, (const float*)nullptr,
                       1024, 2048, 1024, 1024, 0,
                       1048576LL, 65536LL, 64LL, 64LL, 0LL, 1.0f);
    hipLaunchKernelGGL((gemm_bf16_nt<false>), dim3(16, 1, NG), dim3(256), 0, stream,
                       (const unsigned short*)scoresT, vT2_bf, (void*)out_ctx, b_conv, (const float*)nullptr,
                       512, 1024, 512, 1024, 0,
                       1048576LL, 32768LL, 64LL, 64LL, 0LL, 1.0f);
}

// Round 3
// 220.355 us; speedup vs baseline: 2.2339x; 1.2894x over previous
//
#include <hip/hip_runtime.h>
#include <math.h>

// M=512, N=1024, G=16, D=64, C=1024. All GEMMs bf16 MFMA 16x16x32, fp32 acc.
//
// Workspace map (float offsets; shorts = 2x floats). Peak 36,438,016 floats = 145.8 MB.
//   pool0 shorts [0, 3145728) over floats [0, 1572864):
//     feat_bf @0 (524288 s) | ctx_bf @524288 (1048576 s)   <- contiguous 1536-row A
//     q_bf @1572864 (524288 s) | k_bf @2097152 (1048576 s) <- contiguous 1536-row C
//   scores  : floats [1572864, 9961472)   (G,M,N) logits -> softmax packs bf16 in place
//     (wfcgt_bf/wfcctx_bf transient in first 2M shorts until proj done)
//   scoresT : floats [9961472, 18350080)  (G,N,M)
//   bias_gt : floats [18350080, 26738688)
//   bias_ctx: floats [26738688, 35127296)
//   tail shorts from float 35127296: wconv_bf (1048576 s), vt_bf (G,64,1536) (1572864 s)
//     vt cols 0..511 = feat-sourced (for out_ctx), 512..1535 = ctx-sourced (for out_gt)

typedef __attribute__((ext_vector_type(8))) short short8;   // 8 bf16 = 4 VGPRs
typedef __attribute__((ext_vector_type(4))) float floatx4;

__device__ inline unsigned short f32_bf16_rne(float x) {
    union { float f; unsigned u; } v; v.f = x;
    unsigned u = v.u;
    return (unsigned short)((u + 0x7fffu + ((u >> 16) & 1u)) >> 16);
}

__device__ __forceinline__ floatx4 mfma16(short8 a, short8 b, floatx4 c) {
    return __builtin_amdgcn_mfma_f32_16x16x32_bf16(a, b, c, 0, 0, 0);
}

// ---------------------------------------------------------------------------
// 64x64 tile NT bf16 GEMM core. 4 waves, each a 32x32 quadrant. BK=64, register
// prefetch one chunk ahead (global load overlaps MFMA+ds_read phase).
// C[i][j] = alpha * sum_k A[i][k]B[j][k] + biasvec[j] + addmat[i][j]
// K %64==0, lda/ldb %8==0; pointers pre-offset to the block's tile origin.
// ---------------------------------------------------------------------------
template <bool OUT_BF16>
__device__ __forceinline__ void gemm_tile(
    const unsigned short* __restrict__ Ab, int lda,
    const unsigned short* __restrict__ Bb, int ldb, int K,
    void* __restrict__ Cb, int ldc,
    const float* __restrict__ biasvec,
    const float* __restrict__ addmat, int ldadd, float alpha,
    unsigned short* As, unsigned short* Bs)
{
    const int tid = threadIdx.x;
    const int lr = tid >> 2;          // loader row 0..63
    const int lk = (tid & 3) * 8;     // loader k: 0,8,16,24 shorts (+32 second half)
    const int lane = tid & 63;
    const int wave = tid >> 6;
    const int qr = (wave >> 1) * 32;
    const int qc = (wave & 1) * 32;
    const int m = lane & 15;
    const int quad = lane >> 4;

    const unsigned short* Ap = Ab + (long long)lr * lda + lk;
    const unsigned short* Bp = Bb + (long long)lr * ldb + lk;
    unsigned short* AsW = As + lr * 72 + lk;      // 72-short row stride: 144B, 16B-aligned
    unsigned short* BsW = Bs + lr * 72 + lk;
    const unsigned short* a0p = As + (qr + m) * 72 + quad * 8;
    const unsigned short* b0p = Bs + (qc + m) * 72 + quad * 8;

    floatx4 acc00 = {0.f,0.f,0.f,0.f}, acc01 = {0.f,0.f,0.f,0.f};
    floatx4 acc10 = {0.f,0.f,0.f,0.f}, acc11 = {0.f,0.f,0.f,0.f};

    int4 pa0 = *(const int4*)Ap;
    int4 pa1 = *(const int4*)(Ap + 32);
    int4 pb0 = *(const int4*)Bp;
    int4 pb1 = *(const int4*)(Bp + 32);

    for (int k0 = 0; ; ) {
        __syncthreads();
        *(int4*)AsW        = pa0;
        *(int4*)(AsW + 32) = pa1;
        *(int4*)BsW        = pb0;
        *(int4*)(BsW + 32) = pb1;
        __syncthreads();
        const int kn = k0 + 64;
        if (kn < K) {            // prefetch next chunk; waited-on only at next store
            pa0 = *(const int4*)(Ap + kn);
            pa1 = *(const int4*)(Ap + kn + 32);
            pb0 = *(const int4*)(Bp + kn);
            pb1 = *(const int4*)(Bp + kn + 32);
        }
        #pragma unroll
        for (int kk = 0; kk < 64; kk += 32) {
            short8 a0 = *(const short8*)(a0p + kk);
            short8 a1 = *(const short8*)(a0p + 16 * 72 + kk);
            short8 b0 = *(const short8*)(b0p + kk);
            short8 b1 = *(const short8*)(b0p + 16 * 72 + kk);
            acc00 = mfma16(a0, b0, acc00);
            acc01 = mfma16(a0, b1, acc01);
            acc10 = mfma16(a1, b0, acc10);
            acc11 = mfma16(a1, b1, acc11);
        }
        k0 = kn;
        if (k0 >= K) break;
    }

    float bias0 = 0.f, bias1 = 0.f;
    if (biasvec) { bias0 = biasvec[qc + m]; bias1 = biasvec[qc + 16 + m]; }

    const floatx4 accs[2][2] = { {acc00, acc01}, {acc10, acc11} };
    #pragma unroll
    for (int i = 0; i < 2; ++i) {
        #pragma unroll
        for (int r = 0; r < 4; ++r) {
            const int lrow = qr + i * 16 + quad * 4 + r;
            #pragma unroll
            for (int j = 0; j < 2; ++j) {
                const int lcol = qc + j * 16 + m;
                float val = fmaf(alpha, accs[i][j][r], j ? bias1 : bias0);
                if (addmat) val += addmat[(long long)lrow * ldadd + lcol];
                if (OUT_BF16)
                    ((unsigned short*)Cb)[(long long)lrow * ldc + lcol] = f32_bf16_rne(val);
                else
                    ((float*)Cb)[(long long)lrow * ldc + lcol] = val;
            }
        }
    }
}

// ---------------------------------------------------------------------------
// Merged q/k projection: rows 0..511 = feat @ w_fc_gt^T, rows 512..1535 = ctx @ w_fc_ctx^T
// ---------------------------------------------------------------------------
__global__ __launch_bounds__(256) void proj_kernel(
    const unsigned short* __restrict__ in_bf, const unsigned short* __restrict__ wgt,
    const unsigned short* __restrict__ wctx,
    const float* __restrict__ bgt, const float* __restrict__ bctx,
    unsigned short* __restrict__ qk)
{
    __shared__ __align__(16) unsigned short As[64 * 72];
    __shared__ __align__(16) unsigned short Bs[64 * 72];
    const int bm = blockIdx.x * 64, bn = blockIdx.y * 64;
    const unsigned short* B = (bm < 512) ? wgt : wctx;
    const float* bias = (bm < 512) ? bgt : bctx;
    gemm_tile<true>(in_bf + (long long)bm * 1024, 1024,
                    B + (long long)bn * 1024, 1024, 1024,
                    qk + (long long)bm * 1024 + bn, 1024,
                    bias + bn, nullptr, 0, 1.0f, As, Bs);
}

// ---------------------------------------------------------------------------
// Merged scores: z<16 -> scores[g]=q_g k_g^T/8 + bias_gt ; z>=16 -> transposed dir
// ---------------------------------------------------------------------------
__global__ __launch_bounds__(256) void scores_kernel(
    const unsigned short* __restrict__ q, const unsigned short* __restrict__ k,
    float* __restrict__ scores, float* __restrict__ scoresT,
    const float* __restrict__ bias_gt, const float* __restrict__ bias_ctx)
{
    __shared__ __align__(16) unsigned short As[64 * 72];
    __shared__ __align__(16) unsigned short Bs[64 * 72];
    const int z = blockIdx.z;
    const int bm = blockIdx.x * 64, bn = blockIdx.y * 64;
    if (z < 16) {
        if (bm >= 512) return;
        const int g = z;
        gemm_tile<false>(q + g * 64 + (long long)bm * 1024, 1024,
                         k + g * 64 + (long long)bn * 1024, 1024, 64,
                         scores + (long long)g * 524288 + (long long)bm * 1024 + bn, 1024,
                         nullptr,
                         bias_gt + (long long)g * 524288 + (long long)bm * 1024 + bn, 1024,
                         0.125f, As, Bs);
    } else {
        if (bn >= 512) return;
        const int g = z - 16;
        gemm_tile<false>(k + g * 64 + (long long)bm * 1024, 1024,
                         q + g * 64 + (long long)bn * 1024, 1024, 64,
                         scoresT + (long long)g * 524288 + (long long)bm * 512 + bn, 512,
                         nullptr,
                         bias_ctx + (long long)g * 524288 + (long long)bm * 512 + bn, 512,
                         0.125f, As, Bs);
    }
}

// ---------------------------------------------------------------------------
// Merged v-projection: vt[g][o][c] = w_conv[g][o] . in_bf[c]  (c over 1536 rows)
// ---------------------------------------------------------------------------
__global__ __launch_bounds__(256) void vt_kernel(
    const unsigned short* __restrict__ wconv, const unsigned short* __restrict__ in_bf,
    unsigned short* __restrict__ vt)
{
    __shared__ __align__(16) unsigned short As[64 * 72];
    __shared__ __align__(16) unsigned short Bs[64 * 72];
    const int g = blockIdx.z;
    const int bn = blockIdx.y * 64;
    gemm_tile<true>(wconv + (long long)g * 65536, 1024,
                    in_bf + (long long)bn * 1024, 1024, 1024,
                    vt + (long long)g * 98304 + bn, 1536,
                    nullptr, nullptr, 0, 1.0f, As, Bs);
}

// ---------------------------------------------------------------------------
// Merged output GEMMs. A = softmax weights packed bf16 inside fp32 score rows.
// z<16: out_gt[m][g*64+o] = sum_n w1[g][m][n] vt[g][o][512+n] + b_conv
// z>=16: out_ctx[n][g*64+o] = sum_m w2[g][n][m] vt[g][o][m] + b_conv
// ---------------------------------------------------------------------------
__global__ __launch_bounds__(256) void out_kernel(
    const unsigned short* __restrict__ scores_p, const unsigned short* __restrict__ scoresT_p,
    const unsigned short* __restrict__ vt, const float* __restrict__ b_conv,
    float* __restrict__ out_gt, float* __restrict__ out_ctx)
{
    __shared__ __align__(16) unsigned short As[64 * 72];
    __shared__ __align__(16) unsigned short Bs[64 * 72];
    const int z = blockIdx.z;
    const int bm = blockIdx.x * 64;
    if (z < 16) {
        if (bm >= 512) return;
        const int g = z;
        gemm_tile<false>(scores_p + (long long)g * 1048576 + (long long)bm * 2048, 2048,
                         vt + (long long)g * 98304 + 512, 1536, 1024,
                         out_gt + (long long)bm * 1024 + g * 64, 1024,
                         b_conv + g * 64, nullptr, 0, 1.0f, As, Bs);
    } else {
        const int g = z - 16;
        gemm_tile<false>(scoresT_p + (long long)g * 1048576 + (long long)bm * 1024, 1024,
                         vt + (long long)g * 98304, 1536, 512,
                         out_ctx + (long long)bm * 1024 + g * 64, 1024,
                         b_conv + g * 64, nullptr, 0, 1.0f, As, Bs);
    }
}

// ---------------------------------------------------------------------------
// fp32 -> bf16 cast for 5 tensors in one launch.
// ---------------------------------------------------------------------------
__global__ __launch_bounds__(256) void conv5_f32_bf16(
    const float* s0, unsigned short* d0, int n0,
    const float* s1, unsigned short* d1, int n1,
    const float* s2, unsigned short* d2, int n2,
    const float* s3, unsigned short* d3, int n3,
    const float* s4, unsigned short* d4, int n4)
{
    const float* s; unsigned short* d; int n;
    switch (blockIdx.y) {
        case 0: s = s0; d = d0; n = n0; break;
        case 1: s = s1; d = d1; n = n1; break;
        case 2: s = s2; d = d2; n = n2; break;
        case 3: s = s3; d = d3; n = n3; break;
        default: s = s4; d = d4; n = n4; break;
    }
    int idx = (blockIdx.x * 256 + threadIdx.x) * 4;
    if (idx < n) {
        float4 v = *(const float4*)(s + idx);
        ushort4 o;
        o.x = f32_bf16_rne(v.x); o.y = f32_bf16_rne(v.y);
        o.z = f32_bf16_rne(v.z); o.w = f32_bf16_rne(v.w);
        *(ushort4*)(d + idx) = o;
    }
}

// ---------------------------------------------------------------------------
// Merged position-bias logits (both directions): blocks <2048 gt, else ctx.
// ---------------------------------------------------------------------------
__global__ __launch_bounds__(256) void pos_bias_kernel(
    const float* __restrict__ box, const float* __restrict__ ctx_box,
    const float* __restrict__ w_gt, const float* __restrict__ b_gt,
    const float* __restrict__ w_ctx, const float* __restrict__ b_ctx,
    float* __restrict__ bias_gt, float* __restrict__ bias_ctx)
{
    const bool first = blockIdx.x < 2048;
    const float* boxA = first ? box : ctx_box;
    const float* boxB = first ? ctx_box : box;
    const float* w_pos = first ? w_gt : w_ctx;
    const float* b_pos = first ? b_gt : b_ctx;
    float* out = first ? bias_gt : bias_ctx;
    const int nrows = first ? 512 : 1024;
    const int shift = first ? 10 : 9;
    const long long blk = first ? blockIdx.x : (blockIdx.x - 2048);

    __shared__ float wt[64 * 16];            // wt[i*16+g] = w_pos[g*64+i]
    const int tid = threadIdx.x;
    for (int t = tid; t < 1024; t += 256) {
        int g = t >> 6, i = t & 63;
        wt[i * 16 + g] = w_pos[t];
    }
    __syncthreads();

    const int ncols = 1 << shift;
    const long long idx = blk * 256 + tid;
    const int i = (int)(idx >> shift);
    const int j = (int)(idx & (ncols - 1));

    float4 ba = *(const float4*)(boxA + i * 4);
    float4 bb = *(const float4*)(boxB + j * 4);
    float bw = ba.z - ba.x + 1.f, bh = ba.w - ba.y + 1.f;
    float cx = 0.5f * (ba.x + ba.z), cy = 0.5f * (ba.y + ba.w);
    float cbw = bb.z - bb.x + 1.f, cbh = bb.w - bb.y + 1.f;
    float ccx = 0.5f * (bb.x + bb.z), ccy = 0.5f * (bb.y + bb.w);

    float pos4[4];
    pos4[0] = logf(fmaxf(fabsf((cx - ccx) / bw), 1e-3f));
    pos4[1] = logf(fmaxf(fabsf((cy - ccy) / bh), 1e-3f));
    pos4[2] = logf(cbw / bw);
    pos4[3] = logf(cbh / bh);

    const float inv_dim[8] = {
        1.0f, 0.42169650342f, 0.17782794100f, 0.07498942093f,
        0.03162277660f, 0.01333521432f, 0.00562341325f, 0.00237137371f };

    float acc[16];
    #pragma unroll
    for (int g = 0; g < 16; ++g) acc[g] = b_pos[g];

    #pragma unroll
    for (int p = 0; p < 4; ++p) {
        float base = 100.f * pos4[p];
        #pragma unroll
        for (int f = 0; f < 8; ++f) {
            float t = base * inv_dim[f];
            float s, c;
            __sincosf(t, &s, &c);
            float rs = fmaxf(s, 0.f);
            float rc = fmaxf(c, 0.f);
            const float4* w4s = (const float4*)&wt[(p * 16 + f) * 16];
            const float4* w4c = (const float4*)&wt[(p * 16 + 8 + f) * 16];
            #pragma unroll
            for (int q = 0; q < 4; ++q) {
                float4 ws4 = w4s[q];
                float4 wc4 = w4c[q];
                acc[4*q+0] = fmaf(rs, ws4.x, acc[4*q+0]);
                acc[4*q+1] = fmaf(rs, ws4.y, acc[4*q+1]);
                acc[4*q+2] = fmaf(rs, ws4.z, acc[4*q+2]);
                acc[4*q+3] = fmaf(rs, ws4.w, acc[4*q+3]);
                acc[4*q+0] = fmaf(rc, wc4.x, acc[4*q+0]);
                acc[4*q+1] = fmaf(rc, wc4.y, acc[4*q+1]);
                acc[4*q+2] = fmaf(rc, wc4.z, acc[4*q+2]);
                acc[4*q+3] = fmaf(rc, wc4.w, acc[4*q+3]);
            }
        }
    }

    const long long plane = (long long)nrows << shift;
    #pragma unroll
    for (int g = 0; g < 16; ++g)
        out[(long long)g * plane + idx] = logf(fmaxf(acc[g], 1e-6f));
}

// ---------------------------------------------------------------------------
// Merged row softmax; packs bf16 result in place over the fp32 rows.
// ---------------------------------------------------------------------------
template <int CNT>
__device__ __forceinline__ void softmax_row(float* __restrict__ d)
{
    const int tid = threadIdx.x;
    float v[CNT];
    float mx = -1e30f;
    #pragma unroll
    for (int c = 0; c < CNT; ++c) {
        v[c] = d[tid + 256 * c];
        mx = fmaxf(mx, v[c]);
    }
    #pragma unroll
    for (int off = 32; off >= 1; off >>= 1)
        mx = fmaxf(mx, __shfl_xor(mx, off, 64));

    __shared__ float redm[4], reds[4];
    if ((tid & 63) == 0) redm[tid >> 6] = mx;
    __syncthreads();
    mx = fmaxf(fmaxf(redm[0], redm[1]), fmaxf(redm[2], redm[3]));

    float sum = 0.f;
    #pragma unroll
    for (int c = 0; c < CNT; ++c) { v[c] = __expf(v[c] - mx); sum += v[c]; }
    #pragma unroll
    for (int off = 32; off >= 1; off >>= 1)
        sum += __shfl_xor(sum, off, 64);
    if ((tid & 63) == 0) reds[tid >> 6] = sum;
    __syncthreads();   // all fp32 reads complete before bf16 writes
    sum = reds[0] + reds[1] + reds[2] + reds[3];

    float inv = 1.0f / sum;
    unsigned short* o = (unsigned short*)d;
    #pragma unroll
    for (int c = 0; c < CNT; ++c)
        o[tid + 256 * c] = f32_bf16_rne(v[c] * inv);
}

__global__ __launch_bounds__(256) void softmax_kernel(
    float* __restrict__ scores, float* __restrict__ scoresT)
{
    const long long b = blockIdx.x;
    if (b < 8192) softmax_row<4>(scores + b * 1024);
    else          softmax_row<2>(scoresT + (b - 8192) * 512);
}

// ---------------------------------------------------------------------------
extern "C" void kernel_launch(void* const* d_in, const int* in_sizes, int n_in,
                              void* d_out, int out_size, void* d_ws, size_t ws_size,
                              hipStream_t stream)
{
    const float* feat     = (const float*)d_in[0];
    const float* ctx_feat = (const float*)d_in[1];
    const float* box      = (const float*)d_in[2];
    const float* ctx_box  = (const float*)d_in[3];
    const float* w_fc_gt  = (const float*)d_in[4];
    const float* b_fc_gt  = (const float*)d_in[5];
    const float* w_fc_ctx = (const float*)d_in[6];
    const float* b_fc_ctx = (const float*)d_in[7];
    const float* w_pos_gt = (const float*)d_in[8];
    const float* b_pos_gt = (const float*)d_in[9];
    const float* w_pos_ctx= (const float*)d_in[10];
    const float* b_pos_ctx= (const float*)d_in[11];
    const float* w_conv   = (const float*)d_in[12];
    const float* b_conv   = (const float*)d_in[13];

    float* ws = (float*)d_ws;
    unsigned short* pool0   = (unsigned short*)ws;
    unsigned short* in_bf   = pool0;                  // feat(524288) + ctx(1048576)
    unsigned short* ctx_bf  = pool0 + 524288LL;
    unsigned short* qk_bf   = pool0 + 1572864LL;      // q(524288) + k(1048576)
    unsigned short* k_bf    = pool0 + 2097152LL;

    float* scores   = ws + 1572864LL;
    float* scoresT  = ws + 9961472LL;
    float* bias_gt  = ws + 18350080LL;
    float* bias_ctx = ws + 26738688LL;

    unsigned short* wfcgt_bf  = (unsigned short*)scores;           // transient
    unsigned short* wfcctx_bf = (unsigned short*)scores + 1048576LL;

    unsigned short* wconv_bf = (unsigned short*)(ws + 35127296LL);
    unsigned short* vt_bf    = wconv_bf + 1048576LL;   // (G,64,1536)

    float* out_gt  = (float*)d_out;
    float* out_ctx = (float*)d_out + 524288LL;

    // 1) casts (feat & ctx contiguous for merged A operands)
    hipLaunchKernelGGL(conv5_f32_bf16, dim3(1024, 5), dim3(256), 0, stream,
                       feat, in_bf, 524288,
                       ctx_feat, ctx_bf, 1048576,
                       w_fc_gt, wfcgt_bf, 1048576,
                       w_fc_ctx, wfcctx_bf, 1048576,
                       w_conv, wconv_bf, 1048576);

    // 2) position bias logits (both directions, one launch)
    hipLaunchKernelGGL(pos_bias_kernel, dim3(4096), dim3(256), 0, stream,
                       box, ctx_box, w_pos_gt, b_pos_gt, w_pos_ctx, b_pos_ctx,
                       bias_gt, bias_ctx);

    // 3) merged q/k projection (384 blocks, K=1024)
    hipLaunchKernelGGL(proj_kernel, dim3(24, 16), dim3(256), 0, stream,
                       in_bf, wfcgt_bf, wfcctx_bf, b_fc_gt, b_fc_ctx, qk_bf);

    // 4) merged v-projection (384 blocks, K=1024)
    hipLaunchKernelGGL(vt_kernel, dim3(1, 24, 16), dim3(256), 0, stream,
                       wconv_bf, in_bf, vt_bf);

    // 5) merged scores + bias (K=64, write-bound)
    hipLaunchKernelGGL(scores_kernel, dim3(16, 16, 32), dim3(256), 0, stream,
                       qk_bf, k_bf, scores, scoresT, bias_gt, bias_ctx);

    // 6) merged softmax -> bf16 packed in place
    hipLaunchKernelGGL(softmax_kernel, dim3(24576), dim3(256), 0, stream,
                       scores, scoresT);

    // 7) merged outputs (384 active blocks, K=1024/512)
    hipLaunchKernelGGL(out_kernel, dim3(16, 1, 32), dim3(256), 0, stream,
                       (const unsigned short*)scores, (const unsigned short*)scoresT,
                       vt_bf, b_conv, out_gt, out_ctx);
}

// Round 5
// 194.308 us; speedup vs baseline: 2.5334x; 1.1341x over previous
//
#include <hip/hip_runtime.h>
#include <math.h>

// M=512, N=1024, G=16, D=64, C=1024. All GEMM-shaped work on bf16 MFMA 16x16x32,
// EXCEPT the position-bias dot which stays fp32 VALU (log() amplifies small-dot
// relative error; bf16 dot was round-4's suspected failure).
//
// Pipeline (6 launches):
//   conv5      : fp32->bf16 casts (feat, ctx, w_fc_gt, w_fc_ctx, w_conv)
//   pos_bias   : fp32 dot (round-3-proven body) -> log-clip -> fp16 bias planes
//   proj       : qk = [feat;ctx] @ [w_fc_gt;w_fc_ctx]^T + b   (gemm_tile)
//   vt         : vt[g][o][c] = w_conv[g][o] . [feat;ctx][c]   (gemm_tile)
//   attn_out   : per (g, 16 rows): scores (MFMA) + fp16 bias -> softmax (regs)
//                -> bf16 weights in LDS -> out-GEMM vs vt -> d_out  (x2 dirs)
//
// Workspace (float offsets), total 12,320,768 floats = 49.3 MB:
//   [0,1572864)        : shorts: in_bf (feat 524288 + ctx 1048576), qk_bf (1572864)
//   [1572864,5767168)  : bias_gt  fp16 (16,512,1024)
//   [5767168,9961472)  : bias_ctx fp16 (16,1024,512)
//   [9961472,10485760) : wconv_bf (1048576 s)
//   [10485760,11272192): vt_bf (G,64,1536) shorts; cols 0..511 feat, 512..1535 ctx
//   [11272192,12320768): wfcgt_bf + wfcctx_bf

typedef __attribute__((ext_vector_type(8))) short short8;   // 8 bf16 = 4 VGPRs
typedef __attribute__((ext_vector_type(4))) float floatx4;

__device__ inline unsigned short f32_bf16_rne(float x) {
    union { float f; unsigned u; } v; v.f = x;
    unsigned u = v.u;
    return (unsigned short)((u + 0x7fffu + ((u >> 16) & 1u)) >> 16);
}

__device__ __forceinline__ floatx4 mfma16(short8 a, short8 b, floatx4 c) {
    return __builtin_amdgcn_mfma_f32_16x16x32_bf16(a, b, c, 0, 0, 0);
}

// ---------------------------------------------------------------------------
// 64x64 tile NT bf16 GEMM core (proj / vt). 4 waves, 32x32 quadrant each,
// BK=64 with register prefetch. Writes bf16. K%64==0, lda/ldb%8==0.
// ---------------------------------------------------------------------------
__device__ __forceinline__ void gemm_tile_bf16(
    const unsigned short* __restrict__ Ab, int lda,
    const unsigned short* __restrict__ Bb, int ldb, int K,
    unsigned short* __restrict__ Cb, int ldc,
    const float* __restrict__ biasvec,
    unsigned short* As, unsigned short* Bs)
{
    const int tid = threadIdx.x;
    const int lr = tid >> 2;
    const int lk = (tid & 3) * 8;
    const int lane = tid & 63;
    const int wave = tid >> 6;
    const int qr = (wave >> 1) * 32;
    const int qc = (wave & 1) * 32;
    const int m = lane & 15;
    const int quad = lane >> 4;

    const unsigned short* Ap = Ab + (long long)lr * lda + lk;
    const unsigned short* Bp = Bb + (long long)lr * ldb + lk;
    unsigned short* AsW = As + lr * 72 + lk;
    unsigned short* BsW = Bs + lr * 72 + lk;
    const unsigned short* a0p = As + (qr + m) * 72 + quad * 8;
    const unsigned short* b0p = Bs + (qc + m) * 72 + quad * 8;

    floatx4 acc00 = {0.f,0.f,0.f,0.f}, acc01 = {0.f,0.f,0.f,0.f};
    floatx4 acc10 = {0.f,0.f,0.f,0.f}, acc11 = {0.f,0.f,0.f,0.f};

    int4 pa0 = *(const int4*)Ap;
    int4 pa1 = *(const int4*)(Ap + 32);
    int4 pb0 = *(const int4*)Bp;
    int4 pb1 = *(const int4*)(Bp + 32);

    for (int k0 = 0; ; ) {
        __syncthreads();
        *(int4*)AsW        = pa0;
        *(int4*)(AsW + 32) = pa1;
        *(int4*)BsW        = pb0;
        *(int4*)(BsW + 32) = pb1;
        __syncthreads();
        const int kn = k0 + 64;
        if (kn < K) {
            pa0 = *(const int4*)(Ap + kn);
            pa1 = *(const int4*)(Ap + kn + 32);
            pb0 = *(const int4*)(Bp + kn);
            pb1 = *(const int4*)(Bp + kn + 32);
        }
        #pragma unroll
        for (int kk = 0; kk < 64; kk += 32) {
            short8 a0 = *(const short8*)(a0p + kk);
            short8 a1 = *(const short8*)(a0p + 16 * 72 + kk);
            short8 b0 = *(const short8*)(b0p + kk);
            short8 b1 = *(const short8*)(b0p + 16 * 72 + kk);
            acc00 = mfma16(a0, b0, acc00);
            acc01 = mfma16(a0, b1, acc01);
            acc10 = mfma16(a1, b0, acc10);
            acc11 = mfma16(a1, b1, acc11);
        }
        k0 = kn;
        if (k0 >= K) break;
    }

    float bias0 = 0.f, bias1 = 0.f;
    if (biasvec) { bias0 = biasvec[qc + m]; bias1 = biasvec[qc + 16 + m]; }

    const floatx4 accs[2][2] = { {acc00, acc01}, {acc10, acc11} };
    #pragma unroll
    for (int i = 0; i < 2; ++i)
        #pragma unroll
        for (int r = 0; r < 4; ++r) {
            const int lrow = qr + i * 16 + quad * 4 + r;
            #pragma unroll
            for (int j = 0; j < 2; ++j) {
                const int lcol = qc + j * 16 + m;
                float val = accs[i][j][r] + (j ? bias1 : bias0);
                Cb[(long long)lrow * ldc + lcol] = f32_bf16_rne(val);
            }
        }
}

// Merged q/k projection.
__global__ __launch_bounds__(256) void proj_kernel(
    const unsigned short* __restrict__ in_bf, const unsigned short* __restrict__ wgt,
    const unsigned short* __restrict__ wctx,
    const float* __restrict__ bgt, const float* __restrict__ bctx,
    unsigned short* __restrict__ qk)
{
    __shared__ __align__(16) unsigned short As[64 * 72];
    __shared__ __align__(16) unsigned short Bs[64 * 72];
    const int bm = blockIdx.x * 64, bn = blockIdx.y * 64;
    const unsigned short* B = (bm < 512) ? wgt : wctx;
    const float* bias = (bm < 512) ? bgt : bctx;
    gemm_tile_bf16(in_bf + (long long)bm * 1024, 1024,
                   B + (long long)bn * 1024, 1024, 1024,
                   qk + (long long)bm * 1024 + bn, 1024,
                   bias + bn, As, Bs);
}

// Merged v-projection: vt[g][o][c], c over 1536 concat rows.
__global__ __launch_bounds__(256) void vt_kernel(
    const unsigned short* __restrict__ wconv, const unsigned short* __restrict__ in_bf,
    unsigned short* __restrict__ vt)
{
    __shared__ __align__(16) unsigned short As[64 * 72];
    __shared__ __align__(16) unsigned short Bs[64 * 72];
    const int g = blockIdx.z;
    const int bn = blockIdx.y * 64;
    gemm_tile_bf16(wconv + (long long)g * 65536, 1024,
                   in_bf + (long long)bn * 1024, 1024, 1024,
                   vt + (long long)g * 98304 + bn, 1536,
                   nullptr, As, Bs);
}

// ---------------------------------------------------------------------------
// Position-bias logits, round-3-proven fp32-dot body. One thread per pair.
// blocks <2048 -> gt plane, else ctx plane. Output fp16.
// ---------------------------------------------------------------------------
__global__ __launch_bounds__(256) void pos_bias_kernel(
    const float* __restrict__ box, const float* __restrict__ ctx_box,
    const float* __restrict__ w_gt, const float* __restrict__ b_gt,
    const float* __restrict__ w_ctx, const float* __restrict__ b_ctx,
    _Float16* __restrict__ bias_gt, _Float16* __restrict__ bias_ctx)
{
    const bool first = blockIdx.x < 2048;
    const float* boxA = first ? box : ctx_box;
    const float* boxB = first ? ctx_box : box;
    const float* w_pos = first ? w_gt : w_ctx;
    const float* b_pos = first ? b_gt : b_ctx;
    _Float16* out = first ? bias_gt : bias_ctx;
    const int shift = first ? 10 : 9;
    const long long blk = first ? blockIdx.x : (blockIdx.x - 2048);

    __shared__ float wt[64 * 16];            // wt[i*16+g] = w_pos[g*64+i]
    const int tid = threadIdx.x;
    for (int t = tid; t < 1024; t += 256) {
        int g = t >> 6, i = t & 63;
        wt[i * 16 + g] = w_pos[t];
    }
    __syncthreads();

    const int ncols = 1 << shift;
    const long long idx = blk * 256 + tid;
    const int i = (int)(idx >> shift);
    const int j = (int)(idx & (ncols - 1));

    float4 ba = *(const float4*)(boxA + i * 4);
    float4 bb = *(const float4*)(boxB + j * 4);
    float bw = ba.z - ba.x + 1.f, bh = ba.w - ba.y + 1.f;
    float cx = 0.5f * (ba.x + ba.z), cy = 0.5f * (ba.y + ba.w);
    float cbw = bb.z - bb.x + 1.f, cbh = bb.w - bb.y + 1.f;
    float ccx = 0.5f * (bb.x + bb.z), ccy = 0.5f * (bb.y + bb.w);

    float pos4[4];
    pos4[0] = __logf(fmaxf(fabsf((cx - ccx) / bw), 1e-3f));
    pos4[1] = __logf(fmaxf(fabsf((cy - ccy) / bh), 1e-3f));
    pos4[2] = __logf(cbw / bw);
    pos4[3] = __logf(cbh / bh);

    const float inv_dim[8] = {
        1.0f, 0.42169650342f, 0.17782794100f, 0.07498942093f,
        0.03162277660f, 0.01333521432f, 0.00562341325f, 0.00237137371f };

    float acc[16];
    #pragma unroll
    for (int g = 0; g < 16; ++g) acc[g] = b_pos[g];

    #pragma unroll
    for (int p = 0; p < 4; ++p) {
        float base = 100.f * pos4[p];
        #pragma unroll
        for (int f = 0; f < 8; ++f) {
            float t = base * inv_dim[f];
            float s, c;
            __sincosf(t, &s, &c);
            float rs = fmaxf(s, 0.f);
            float rc = fmaxf(c, 0.f);
            const float4* w4s = (const float4*)&wt[(p * 16 + f) * 16];
            const float4* w4c = (const float4*)&wt[(p * 16 + 8 + f) * 16];
            #pragma unroll
            for (int q = 0; q < 4; ++q) {
                float4 ws4 = w4s[q];
                float4 wc4 = w4c[q];
                acc[4*q+0] = fmaf(rs, ws4.x, acc[4*q+0]);
                acc[4*q+1] = fmaf(rs, ws4.y, acc[4*q+1]);
                acc[4*q+2] = fmaf(rs, ws4.z, acc[4*q+2]);
                acc[4*q+3] = fmaf(rs, ws4.w, acc[4*q+3]);
                acc[4*q+0] = fmaf(rc, wc4.x, acc[4*q+0]);
                acc[4*q+1] = fmaf(rc, wc4.y, acc[4*q+1]);
                acc[4*q+2] = fmaf(rc, wc4.z, acc[4*q+2]);
                acc[4*q+3] = fmaf(rc, wc4.w, acc[4*q+3]);
            }
        }
    }

    const long long plane = 524288LL;   // 512*1024 == 1024*512
    #pragma unroll
    for (int g = 0; g < 16; ++g)
        out[(long long)g * plane + idx] = (_Float16)__logf(fmaxf(acc[g], 1e-6f));
}

// ---------------------------------------------------------------------------
// Fused scores + bias + softmax + output GEMM. Block = (g, 16 A-rows).
// ---------------------------------------------------------------------------
template <int NC>
__global__ __launch_bounds__(256) void attn_out_kernel(
    const unsigned short* __restrict__ qA,   // A-side rows (q for gt, k for ctx)
    const unsigned short* __restrict__ qB,   // B-side rows
    const _Float16* __restrict__ bias,       // (G, rowsA, NC*64)
    const unsigned short* __restrict__ vt,   // (G,64,1536)
    int vt_colbase,
    const float* __restrict__ b_conv,
    float* __restrict__ outp)                // rowsA x 1024, col block g*64
{
    constexpr int NCOL = NC * 64;
    constexpr int WS = NCOL + 8;             // wpack row stride (shorts)

    __shared__ __align__(16) unsigned short tile[64 * 72];
    __shared__ __align__(16) unsigned short wpack[16 * WS];
    __shared__ float redA[4][16];
    __shared__ float redB[4][16];

    const int g = blockIdx.z;
    const int bm = blockIdx.x * 16;
    const int tid = threadIdx.x;
    const int lane = tid & 63;
    const int w = tid >> 6;
    const int m = lane & 15;
    const int quad = lane >> 4;
    const int lr = tid >> 2;
    const int lk = (tid & 3) * 8;

    const long long plane = (long long)NCOL * (gridDim.x * 16);
    const _Float16* bias_g = bias + (long long)g * plane
                           + (long long)(bm + quad * 4) * NCOL + w * 16 + m;

    // A-fragments (q rows), loaded once from global
    const unsigned short* ap = qA + (long long)(bm + m) * 1024 + g * 64 + quad * 8;
    short8 aq0 = *(const short8*)ap;
    short8 aq1 = *(const short8*)(ap + 32);

    const unsigned short* Bp = qB + (long long)lr * 1024 + g * 64 + lk;
    unsigned short* tW = tile + lr * 72 + lk;
    const unsigned short* bq = tile + (w * 16 + m) * 72 + quad * 8;

    float v[NC][4];

    int4 pk0 = *(const int4*)Bp;
    int4 pk1 = *(const int4*)(Bp + 32);

    #pragma unroll
    for (int c = 0; c < NC; ++c) {
        __syncthreads();
        *(int4*)tW        = pk0;
        *(int4*)(tW + 32) = pk1;
        __syncthreads();
        if (c + 1 < NC) {
            const unsigned short* nb = Bp + (long long)(c + 1) * 64 * 1024;
            pk0 = *(const int4*)nb;
            pk1 = *(const int4*)(nb + 32);
        }
        float bv[4];
        #pragma unroll
        for (int r = 0; r < 4; ++r)
            bv[r] = (float)bias_g[(long long)r * NCOL + c * 64];
        short8 kb0 = *(const short8*)bq;
        short8 kb1 = *(const short8*)(bq + 32);
        floatx4 acc = {0.f, 0.f, 0.f, 0.f};
        acc = mfma16(aq0, kb0, acc);
        acc = mfma16(aq1, kb1, acc);
        #pragma unroll
        for (int r = 0; r < 4; ++r)
            v[c][r] = fmaf(0.125f, acc[r], bv[r]);
    }

    // prefetch vt chunk 0 (overlaps softmax)
    const unsigned short* Vp = vt + (long long)g * 98304 + (long long)lr * 1536
                             + vt_colbase + lk;
    int4 pv0 = *(const int4*)Vp;
    int4 pv1 = *(const int4*)(Vp + 32);

    // ---- softmax over rows (row = quad*4+r), cols split: wave w, m, chunk c
    float rmax[4];
    #pragma unroll
    for (int r = 0; r < 4; ++r) {
        float mx = v[0][r];
        #pragma unroll
        for (int c = 1; c < NC; ++c) mx = fmaxf(mx, v[c][r]);
        #pragma unroll
        for (int off = 1; off < 16; off <<= 1)
            mx = fmaxf(mx, __shfl_xor(mx, off, 64));
        rmax[r] = mx;
    }
    if (m == 0) {
        #pragma unroll
        for (int r = 0; r < 4; ++r) redA[w][quad * 4 + r] = rmax[r];
    }
    __syncthreads();
    #pragma unroll
    for (int r = 0; r < 4; ++r)
        rmax[r] = fmaxf(fmaxf(redA[0][quad*4+r], redA[1][quad*4+r]),
                        fmaxf(redA[2][quad*4+r], redA[3][quad*4+r]));

    float rsum[4] = {0.f, 0.f, 0.f, 0.f};
    #pragma unroll
    for (int c = 0; c < NC; ++c)
        #pragma unroll
        for (int r = 0; r < 4; ++r) {
            v[c][r] = __expf(v[c][r] - rmax[r]);
            rsum[r] += v[c][r];
        }
    #pragma unroll
    for (int r = 0; r < 4; ++r)
        #pragma unroll
        for (int off = 1; off < 16; off <<= 1)
            rsum[r] += __shfl_xor(rsum[r], off, 64);
    if (m == 0) {
        #pragma unroll
        for (int r = 0; r < 4; ++r) redB[w][quad * 4 + r] = rsum[r];
    }
    __syncthreads();
    float rinv[4];
    #pragma unroll
    for (int r = 0; r < 4; ++r)
        rinv[r] = 1.f / (redB[0][quad*4+r] + redB[1][quad*4+r] +
                         redB[2][quad*4+r] + redB[3][quad*4+r]);

    #pragma unroll
    for (int c = 0; c < NC; ++c)
        #pragma unroll
        for (int r = 0; r < 4; ++r)
            wpack[(quad * 4 + r) * WS + c * 64 + w * 16 + m] =
                f32_bf16_rne(v[c][r] * rinv[r]);

    // ---- phase 3: out = W @ vt^T
    floatx4 oacc = {0.f, 0.f, 0.f, 0.f};
    const unsigned short* awp = wpack + m * WS + quad * 8;
    #pragma unroll
    for (int kc = 0; kc < NC; ++kc) {
        __syncthreads();   // first iter: wpack writes + last tile reads complete
        *(int4*)tW        = pv0;
        *(int4*)(tW + 32) = pv1;
        __syncthreads();
        if (kc + 1 < NC) {
            const unsigned short* nv = Vp + (kc + 1) * 64;
            pv0 = *(const int4*)nv;
            pv1 = *(const int4*)(nv + 32);
        }
        short8 a0 = *(const short8*)(awp + kc * 64);
        short8 a1 = *(const short8*)(awp + kc * 64 + 32);
        short8 b0 = *(const short8*)bq;
        short8 b1 = *(const short8*)(bq + 32);
        oacc = mfma16(a0, b0, oacc);
        oacc = mfma16(a1, b1, oacc);
    }

    const int o = w * 16 + m;
    const float bc = b_conv[g * 64 + o];
    #pragma unroll
    for (int r = 0; r < 4; ++r)
        outp[(long long)(bm + quad * 4 + r) * 1024 + g * 64 + o] = oacc[r] + bc;
}

// ---------------------------------------------------------------------------
__global__ __launch_bounds__(256) void conv5_f32_bf16(
    const float* s0, unsigned short* d0, int n0,
    const float* s1, unsigned short* d1, int n1,
    const float* s2, unsigned short* d2, int n2,
    const float* s3, unsigned short* d3, int n3,
    const float* s4, unsigned short* d4, int n4)
{
    const float* s; unsigned short* d; int n;
    switch (blockIdx.y) {
        case 0: s = s0; d = d0; n = n0; break;
        case 1: s = s1; d = d1; n = n1; break;
        case 2: s = s2; d = d2; n = n2; break;
        case 3: s = s3; d = d3; n = n3; break;
        default: s = s4; d = d4; n = n4; break;
    }
    int idx = (blockIdx.x * 256 + threadIdx.x) * 4;
    if (idx < n) {
        float4 v = *(const float4*)(s + idx);
        ushort4 o;
        o.x = f32_bf16_rne(v.x); o.y = f32_bf16_rne(v.y);
        o.z = f32_bf16_rne(v.z); o.w = f32_bf16_rne(v.w);
        *(ushort4*)(d + idx) = o;
    }
}

// ---------------------------------------------------------------------------
extern "C" void kernel_launch(void* const* d_in, const int* in_sizes, int n_in,
                              void* d_out, int out_size, void* d_ws, size_t ws_size,
                              hipStream_t stream)
{
    const float* feat     = (const float*)d_in[0];
    const float* ctx_feat = (const float*)d_in[1];
    const float* box      = (const float*)d_in[2];
    const float* ctx_box  = (const float*)d_in[3];
    const float* w_fc_gt  = (const float*)d_in[4];
    const float* b_fc_gt  = (const float*)d_in[5];
    const float* w_fc_ctx = (const float*)d_in[6];
    const float* b_fc_ctx = (const float*)d_in[7];
    const float* w_pos_gt = (const float*)d_in[8];
    const float* b_pos_gt = (const float*)d_in[9];
    const float* w_pos_ctx= (const float*)d_in[10];
    const float* b_pos_ctx= (const float*)d_in[11];
    const float* w_conv   = (const float*)d_in[12];
    const float* b_conv   = (const float*)d_in[13];

    float* ws = (float*)d_ws;
    unsigned short* in_bf   = (unsigned short*)ws;           // 1572864 s
    unsigned short* ctx_bf  = in_bf + 524288LL;
    unsigned short* qk_bf   = in_bf + 1572864LL;             // 1572864 s
    _Float16* bias_gt  = (_Float16*)(ws + 1572864LL);        // 8388608 h
    _Float16* bias_ctx = (_Float16*)(ws + 5767168LL);        // 8388608 h
    unsigned short* wconv_bf = (unsigned short*)(ws + 9961472LL);   // 1048576 s
    unsigned short* vt_bf    = (unsigned short*)(ws + 10485760LL);  // 1572864 s
    unsigned short* wfcgt_bf = (unsigned short*)(ws + 11272192LL);  // 1048576 s
    unsigned short* wfcctx_bf= wfcgt_bf + 1048576LL;                // 1048576 s

    float* out_gt  = (float*)d_out;
    float* out_ctx = (float*)d_out + 524288LL;

    // 1) casts
    hipLaunchKernelGGL(conv5_f32_bf16, dim3(1024, 5), dim3(256), 0, stream,
                       feat, in_bf, 524288,
                       ctx_feat, ctx_bf, 1048576,
                       w_fc_gt, wfcgt_bf, 1048576,
                       w_fc_ctx, wfcctx_bf, 1048576,
                       w_conv, wconv_bf, 1048576);

    // 2) position bias (fp16), fp32-dot proven body
    hipLaunchKernelGGL(pos_bias_kernel, dim3(4096), dim3(256), 0, stream,
                       box, ctx_box, w_pos_gt, b_pos_gt, w_pos_ctx, b_pos_ctx,
                       bias_gt, bias_ctx);

    // 3) q/k projection
    hipLaunchKernelGGL(proj_kernel, dim3(24, 16), dim3(256), 0, stream,
                       in_bf, wfcgt_bf, wfcctx_bf, b_fc_gt, b_fc_ctx, qk_bf);

    // 4) v-projection
    hipLaunchKernelGGL(vt_kernel, dim3(1, 24, 16), dim3(256), 0, stream,
                       wconv_bf, in_bf, vt_bf);

    // 5) fused scores+softmax+output, gt<-ctx direction
    hipLaunchKernelGGL((attn_out_kernel<16>), dim3(32, 1, 16), dim3(256), 0, stream,
                       qk_bf, qk_bf + 524288LL, bias_gt, vt_bf, 512, b_conv, out_gt);

    // 6) fused scores+softmax+output, ctx<-gt direction
    hipLaunchKernelGGL((attn_out_kernel<8>), dim3(64, 1, 16), dim3(256), 0, stream,
                       qk_bf + 524288LL, qk_bf, bias_ctx, vt_bf, 0, b_conv, out_ctx);
}

// Round 7
// 170.991 us; speedup vs baseline: 2.8788x; 1.1364x over previous
//
#include <hip/hip_runtime.h>
#include <math.h>

// M=512, N=1024, G=16, D=64, C=1024. All GEMM-shaped work on bf16 MFMA 16x16x32.
// pos_bias uses a bf16 hi/lo (Dekker) split MFMA: plain bf16 inputs gave dot
// errors ~2e-4 which, in rows where all pos dots < 0 (log-clip floor rows),
// flip signs near zero and move ~20% of softmax mass (rounds 4/6, absmax 0.205).
// hi/lo split gives ~3e-6 absolute dot error == fp32-equivalent.
//
// Pipeline (4 launches):
//   conv5      : fp32->bf16 casts (feat, ctx, w_fc_gt, w_fc_ctx, w_conv)
//   pos_bias   : trig -> hi/lo LDS -> 6x MFMA -> log -> fp16 bias planes
//   projvt     : z=0: qk = [feat;ctx] @ [w_fc]^T + b ; z=1: vt = w_conv @ [feat;ctx]^T
//   attn_out   : per (g, 16 rows): scores (MFMA) + fp16 bias -> softmax (regs)
//                -> bf16 weights in LDS -> out-GEMM vs vt -> d_out (both dirs)
//
// Workspace (float offsets), total 12,320,768 floats = 49.3 MB:
//   [0,1572864)        : shorts: in_bf (feat 524288 + ctx 1048576), qk_bf (1572864)
//   [1572864,5767168)  : bias_gt  fp16 (16,512,1024)
//   [5767168,9961472)  : bias_ctx fp16 (16,1024,512)
//   [9961472,10485760) : wconv_bf (1048576 s)
//   [10485760,11272192): vt_bf (G,64,1536) shorts; cols 0..511 feat, 512..1535 ctx
//   [11272192,12320768): wfcgt_bf + wfcctx_bf

typedef __attribute__((ext_vector_type(8))) short short8;   // 8 bf16 = 4 VGPRs
typedef __attribute__((ext_vector_type(4))) float floatx4;
typedef __attribute__((ext_vector_type(4))) _Float16 half4;

__device__ inline unsigned short f32_bf16_rne(float x) {
    union { float f; unsigned u; } v; v.f = x;
    unsigned u = v.u;
    return (unsigned short)((u + 0x7fffu + ((u >> 16) & 1u)) >> 16);
}

__device__ inline float bf16_f32(unsigned short h) {
    union { unsigned u; float f; } v; v.u = (unsigned)h << 16;
    return v.f;
}

__device__ __forceinline__ floatx4 mfma16(short8 a, short8 b, floatx4 c) {
    return __builtin_amdgcn_mfma_f32_16x16x32_bf16(a, b, c, 0, 0, 0);
}

// ---------------------------------------------------------------------------
// 64x64 tile NT bf16 GEMM core. 4 waves, 32x32 quadrant each, BK=64 with
// register prefetch. Writes bf16. K%64==0, lda/ldb%8==0.
// ---------------------------------------------------------------------------
__device__ __forceinline__ void gemm_tile_bf16(
    const unsigned short* __restrict__ Ab, int lda,
    const unsigned short* __restrict__ Bb, int ldb, int K,
    unsigned short* __restrict__ Cb, int ldc,
    const float* __restrict__ biasvec,
    unsigned short* As, unsigned short* Bs)
{
    const int tid = threadIdx.x;
    const int lr = tid >> 2;
    const int lk = (tid & 3) * 8;
    const int lane = tid & 63;
    const int wave = tid >> 6;
    const int qr = (wave >> 1) * 32;
    const int qc = (wave & 1) * 32;
    const int m = lane & 15;
    const int quad = lane >> 4;

    const unsigned short* Ap = Ab + (long long)lr * lda + lk;
    const unsigned short* Bp = Bb + (long long)lr * ldb + lk;
    unsigned short* AsW = As + lr * 72 + lk;
    unsigned short* BsW = Bs + lr * 72 + lk;
    const unsigned short* a0p = As + (qr + m) * 72 + quad * 8;
    const unsigned short* b0p = Bs + (qc + m) * 72 + quad * 8;

    floatx4 acc00 = {0.f,0.f,0.f,0.f}, acc01 = {0.f,0.f,0.f,0.f};
    floatx4 acc10 = {0.f,0.f,0.f,0.f}, acc11 = {0.f,0.f,0.f,0.f};

    int4 pa0 = *(const int4*)Ap;
    int4 pa1 = *(const int4*)(Ap + 32);
    int4 pb0 = *(const int4*)Bp;
    int4 pb1 = *(const int4*)(Bp + 32);

    for (int k0 = 0; ; ) {
        __syncthreads();
        *(int4*)AsW        = pa0;
        *(int4*)(AsW + 32) = pa1;
        *(int4*)BsW        = pb0;
        *(int4*)(BsW + 32) = pb1;
        __syncthreads();
        const int kn = k0 + 64;
        if (kn < K) {
            pa0 = *(const int4*)(Ap + kn);
            pa1 = *(const int4*)(Ap + kn + 32);
            pb0 = *(const int4*)(Bp + kn);
            pb1 = *(const int4*)(Bp + kn + 32);
        }
        #pragma unroll
        for (int kk = 0; kk < 64; kk += 32) {
            short8 a0 = *(const short8*)(a0p + kk);
            short8 a1 = *(const short8*)(a0p + 16 * 72 + kk);
            short8 b0 = *(const short8*)(b0p + kk);
            short8 b1 = *(const short8*)(b0p + 16 * 72 + kk);
            acc00 = mfma16(a0, b0, acc00);
            acc01 = mfma16(a0, b1, acc01);
            acc10 = mfma16(a1, b0, acc10);
            acc11 = mfma16(a1, b1, acc11);
        }
        k0 = kn;
        if (k0 >= K) break;
    }

    float bias0 = 0.f, bias1 = 0.f;
    if (biasvec) { bias0 = biasvec[qc + m]; bias1 = biasvec[qc + 16 + m]; }

    const floatx4 accs[2][2] = { {acc00, acc01}, {acc10, acc11} };
    #pragma unroll
    for (int i = 0; i < 2; ++i)
        #pragma unroll
        for (int r = 0; r < 4; ++r) {
            const int lrow = qr + i * 16 + quad * 4 + r;
            #pragma unroll
            for (int j = 0; j < 2; ++j) {
                const int lcol = qc + j * 16 + m;
                float val = accs[i][j][r] + (j ? bias1 : bias0);
                Cb[(long long)lrow * ldc + lcol] = f32_bf16_rne(val);
            }
        }
}

// ---------------------------------------------------------------------------
// Merged proj + vt. z=0: qk rows 0..1535 = [feat;ctx] @ w_fc^T + b (w per half).
// z=1: vt[g][o][c] = w_conv[g][o] . in[c], c over 1536 concat rows.
// ---------------------------------------------------------------------------
__global__ __launch_bounds__(256) void projvt_kernel(
    const unsigned short* __restrict__ in_bf, const unsigned short* __restrict__ wgt,
    const unsigned short* __restrict__ wctx,
    const float* __restrict__ bgt, const float* __restrict__ bctx,
    unsigned short* __restrict__ qk,
    const unsigned short* __restrict__ wconv, unsigned short* __restrict__ vt)
{
    __shared__ __align__(16) unsigned short As[64 * 72];
    __shared__ __align__(16) unsigned short Bs[64 * 72];
    if (blockIdx.z == 0) {
        const int bm = blockIdx.x * 64, bn = blockIdx.y * 64;
        const unsigned short* B = (bm < 512) ? wgt : wctx;
        const float* bias = (bm < 512) ? bgt : bctx;
        gemm_tile_bf16(in_bf + (long long)bm * 1024, 1024,
                       B + (long long)bn * 1024, 1024, 1024,
                       qk + (long long)bm * 1024 + bn, 1024,
                       bias + bn, As, Bs);
    } else {
        const int g = blockIdx.y;
        const int bn = blockIdx.x * 64;
        gemm_tile_bf16(wconv + (long long)g * 65536, 1024,
                       in_bf + (long long)bn * 1024, 1024, 1024,
                       vt + (long long)g * 98304 + bn, 1536,
                       nullptr, As, Bs);
    }
}

// ---------------------------------------------------------------------------
// Position bias via hi/lo-split MFMA. Block = 64 pairs. Staging thread
// (pl=tid&63, p=tid>>6) computes emb dims p*16..+15 (8 sin + 8 cos) of pair pl,
// split into bf16 hi + lo planes (16 effective mantissa bits). Dot =
// eH.wH + eH.wL + eL.wH (6 MFMAs), fp32-equivalent (~3e-6 abs error) — plain
// bf16's ~2e-4 error sign-flips entries in log-clip floor rows (rounds 4/6).
// ---------------------------------------------------------------------------
__global__ __launch_bounds__(256) void pos_bias_kernel(
    const float* __restrict__ box, const float* __restrict__ ctx_box,
    const float* __restrict__ w_gt, const float* __restrict__ b_gt,
    const float* __restrict__ w_ctx, const float* __restrict__ b_ctx,
    _Float16* __restrict__ bias_gt, _Float16* __restrict__ bias_ctx)
{
    const bool first = (blockIdx.z == 0);
    const float* boxA = first ? box : ctx_box;
    const float* boxB = first ? ctx_box : box;
    const float* w_pos = first ? w_gt : w_ctx;
    const float* b_pos = first ? b_gt : b_ctx;
    _Float16* out = first ? bias_gt : bias_ctx;
    const int shift = first ? 10 : 9;

    __shared__ __align__(16) unsigned short AsH[64 * 72];
    __shared__ __align__(16) unsigned short AsL[64 * 72];
    __shared__ __align__(16) unsigned short BsH[16 * 72];
    __shared__ __align__(16) unsigned short BsL[16 * 72];

    const int tid = threadIdx.x;

    // stage B: w_pos (16x64 fp32) -> bf16 hi + lo
    {
        const int g = tid >> 4;
        const int d = (tid & 15) * 4;
        float4 wv = *(const float4*)(w_pos + g * 64 + d);
        ushort4 h, l;
        h.x = f32_bf16_rne(wv.x); l.x = f32_bf16_rne(wv.x - bf16_f32(h.x));
        h.y = f32_bf16_rne(wv.y); l.y = f32_bf16_rne(wv.y - bf16_f32(h.y));
        h.z = f32_bf16_rne(wv.z); l.z = f32_bf16_rne(wv.z - bf16_f32(h.z));
        h.w = f32_bf16_rne(wv.w); l.w = f32_bf16_rne(wv.w - bf16_f32(h.w));
        *(ushort4*)&BsH[g * 72 + d] = h;
        *(ushort4*)&BsL[g * 72 + d] = l;
    }

    // stage A: relu(sin/cos) embeddings, hi + lo
    const long long pbase = (long long)blockIdx.x * 64;
    {
        const int pl = tid & 63;
        const int p = tid >> 6;          // wave-uniform: no divergence
        const long long pair = pbase + pl;
        const int i = (int)(pair >> shift);
        const int j = (int)(pair & ((1 << shift) - 1));
        float4 ba = *(const float4*)(boxA + i * 4);
        float4 bb = *(const float4*)(boxB + j * 4);
        float posv;
        if (p == 0) {
            float bw = ba.z - ba.x + 1.f;
            float cx = 0.5f * (ba.x + ba.z), ccx = 0.5f * (bb.x + bb.z);
            posv = __logf(fmaxf(fabsf((cx - ccx) / bw), 1e-3f));
        } else if (p == 1) {
            float bh = ba.w - ba.y + 1.f;
            float cy = 0.5f * (ba.y + ba.w), ccy = 0.5f * (bb.y + bb.w);
            posv = __logf(fmaxf(fabsf((cy - ccy) / bh), 1e-3f));
        } else if (p == 2) {
            float bw = ba.z - ba.x + 1.f, cbw = bb.z - bb.x + 1.f;
            posv = __logf(cbw / bw);
        } else {
            float bh = ba.w - ba.y + 1.f, cbh = bb.w - bb.y + 1.f;
            posv = __logf(cbh / bh);
        }
        // 100 * 1000^(-f/8)
        const float w100[8] = {100.f, 42.169650342f, 17.782794100f, 7.498942093f,
                               3.162277660f, 1.333521432f, 0.562341325f, 0.237137371f};
        short8 sh, sl, ch, cl;
        #pragma unroll
        for (int f = 0; f < 8; ++f) {
            float s, c;
            __sincosf(posv * w100[f], &s, &c);
            s = fmaxf(s, 0.f);
            c = fmaxf(c, 0.f);
            unsigned short hs = f32_bf16_rne(s);
            unsigned short hc = f32_bf16_rne(c);
            sh[f] = (short)hs; sl[f] = (short)f32_bf16_rne(s - bf16_f32(hs));
            ch[f] = (short)hc; cl[f] = (short)f32_bf16_rne(c - bf16_f32(hc));
        }
        *(short8*)&AsH[pl * 72 + p * 16]     = sh;   // d = p*16 + f      (sin)
        *(short8*)&AsH[pl * 72 + p * 16 + 8] = ch;   // d = p*16 + 8 + f  (cos)
        *(short8*)&AsL[pl * 72 + p * 16]     = sl;
        *(short8*)&AsL[pl * 72 + p * 16 + 8] = cl;
    }
    __syncthreads();

    // MFMA: wave w -> pairs w*16..+15 (rows) x groups (cols), K=64, 3 chains
    const int lane = tid & 63;
    const int w = tid >> 6;
    const int m = lane & 15;
    const int quad = lane >> 4;
    const unsigned short* apH = &AsH[(w * 16 + m) * 72 + quad * 8];
    const unsigned short* apL = &AsL[(w * 16 + m) * 72 + quad * 8];
    const unsigned short* bpH = &BsH[m * 72 + quad * 8];
    const unsigned short* bpL = &BsL[m * 72 + quad * 8];
    floatx4 acc = {0.f, 0.f, 0.f, 0.f};
    acc = mfma16(*(const short8*)apH,        *(const short8*)bpH,        acc);
    acc = mfma16(*(const short8*)(apH + 32), *(const short8*)(bpH + 32), acc);
    acc = mfma16(*(const short8*)apH,        *(const short8*)bpL,        acc);
    acc = mfma16(*(const short8*)(apH + 32), *(const short8*)(bpL + 32), acc);
    acc = mfma16(*(const short8*)apL,        *(const short8*)bpH,        acc);
    acc = mfma16(*(const short8*)(apL + 32), *(const short8*)(bpH + 32), acc);

    // C: row = pair local quad*4+r, col = group m
    const float bpv = b_pos[m];
    half4 o;
    #pragma unroll
    for (int r = 0; r < 4; ++r)
        o[r] = (_Float16)__logf(fmaxf(acc[r] + bpv, 1e-6f));
    *(half4*)(out + (long long)m * 524288 + pbase + w * 16 + quad * 4) = o;
}

// ---------------------------------------------------------------------------
// Fused scores + bias + softmax + output GEMM body. Block = (g, 16 A-rows).
// LDS passed in so both template instantiations share one allocation.
// ---------------------------------------------------------------------------
template <int NC>
__device__ __forceinline__ void attn_body(
    int g, int bx,
    const unsigned short* __restrict__ qA, const unsigned short* __restrict__ qB,
    const _Float16* __restrict__ bias, const unsigned short* __restrict__ vt,
    int vt_colbase, const float* __restrict__ b_conv, float* __restrict__ outp,
    unsigned short* tile, unsigned short* wpack, float* redA, float* redB)
{
    constexpr int NCOL = NC * 64;
    constexpr int WS = NCOL + 8;

    const int bm = bx * 16;
    const int tid = threadIdx.x;
    const int lane = tid & 63;
    const int w = tid >> 6;
    const int m = lane & 15;
    const int quad = lane >> 4;
    const int lr = tid >> 2;
    const int lk = (tid & 3) * 8;

    const _Float16* bias_g = bias + (long long)g * 524288
                           + (long long)(bm + quad * 4) * NCOL + w * 16 + m;

    const unsigned short* ap = qA + (long long)(bm + m) * 1024 + g * 64 + quad * 8;
    short8 aq0 = *(const short8*)ap;
    short8 aq1 = *(const short8*)(ap + 32);

    const unsigned short* Bp = qB + (long long)lr * 1024 + g * 64 + lk;
    unsigned short* tW = tile + lr * 72 + lk;
    const unsigned short* bq = tile + (w * 16 + m) * 72 + quad * 8;

    float v[NC][4];

    int4 pk0 = *(const int4*)Bp;
    int4 pk1 = *(const int4*)(Bp + 32);

    #pragma unroll
    for (int c = 0; c < NC; ++c) {
        __syncthreads();
        *(int4*)tW        = pk0;
        *(int4*)(tW + 32) = pk1;
        __syncthreads();
        if (c + 1 < NC) {
            const unsigned short* nb = Bp + (long long)(c + 1) * 64 * 1024;
            pk0 = *(const int4*)nb;
            pk1 = *(const int4*)(nb + 32);
        }
        float bv[4];
        #pragma unroll
        for (int r = 0; r < 4; ++r)
            bv[r] = (float)bias_g[(long long)r * NCOL + c * 64];
        short8 kb0 = *(const short8*)bq;
        short8 kb1 = *(const short8*)(bq + 32);
        floatx4 acc = {0.f, 0.f, 0.f, 0.f};
        acc = mfma16(aq0, kb0, acc);
        acc = mfma16(aq1, kb1, acc);
        #pragma unroll
        for (int r = 0; r < 4; ++r)
            v[c][r] = fmaf(0.125f, acc[r], bv[r]);
    }

    const unsigned short* Vp = vt + (long long)g * 98304 + (long long)lr * 1536
                             + vt_colbase + lk;
    int4 pv0 = *(const int4*)Vp;
    int4 pv1 = *(const int4*)(Vp + 32);

    float rmax[4];
    #pragma unroll
    for (int r = 0; r < 4; ++r) {
        float mx = v[0][r];
        #pragma unroll
        for (int c = 1; c < NC; ++c) mx = fmaxf(mx, v[c][r]);
        #pragma unroll
        for (int off = 1; off < 16; off <<= 1)
            mx = fmaxf(mx, __shfl_xor(mx, off, 64));
        rmax[r] = mx;
    }
    if (m == 0) {
        #pragma unroll
        for (int r = 0; r < 4; ++r) redA[w * 16 + quad * 4 + r] = rmax[r];
    }
    __syncthreads();
    #pragma unroll
    for (int r = 0; r < 4; ++r)
        rmax[r] = fmaxf(fmaxf(redA[quad*4+r], redA[16 + quad*4+r]),
                        fmaxf(redA[32 + quad*4+r], redA[48 + quad*4+r]));

    float rsum[4] = {0.f, 0.f, 0.f, 0.f};
    #pragma unroll
    for (int c = 0; c < NC; ++c)
        #pragma unroll
        for (int r = 0; r < 4; ++r) {
            v[c][r] = __expf(v[c][r] - rmax[r]);
            rsum[r] += v[c][r];
        }
    #pragma unroll
    for (int r = 0; r < 4; ++r)
        #pragma unroll
        for (int off = 1; off < 16; off <<= 1)
            rsum[r] += __shfl_xor(rsum[r], off, 64);
    if (m == 0) {
        #pragma unroll
        for (int r = 0; r < 4; ++r) redB[w * 16 + quad * 4 + r] = rsum[r];
    }
    __syncthreads();
    float rinv[4];
    #pragma unroll
    for (int r = 0; r < 4; ++r)
        rinv[r] = 1.f / (redB[quad*4+r] + redB[16 + quad*4+r] +
                         redB[32 + quad*4+r] + redB[48 + quad*4+r]);

    #pragma unroll
    for (int c = 0; c < NC; ++c)
        #pragma unroll
        for (int r = 0; r < 4; ++r)
            wpack[(quad * 4 + r) * WS + c * 64 + w * 16 + m] =
                f32_bf16_rne(v[c][r] * rinv[r]);

    floatx4 oacc = {0.f, 0.f, 0.f, 0.f};
    const unsigned short* awp = wpack + m * WS + quad * 8;
    #pragma unroll
    for (int kc = 0; kc < NC; ++kc) {
        __syncthreads();
        *(int4*)tW        = pv0;
        *(int4*)(tW + 32) = pv1;
        __syncthreads();
        if (kc + 1 < NC) {
            const unsigned short* nv = Vp + (kc + 1) * 64;
            pv0 = *(const int4*)nv;
            pv1 = *(const int4*)(nv + 32);
        }
        short8 a0 = *(const short8*)(awp + kc * 64);
        short8 a1 = *(const short8*)(awp + kc * 64 + 32);
        short8 b0 = *(const short8*)bq;
        short8 b1 = *(const short8*)(bq + 32);
        oacc = mfma16(a0, b0, oacc);
        oacc = mfma16(a1, b1, oacc);
    }

    const int o = w * 16 + m;
    const float bc = b_conv[g * 64 + o];
    #pragma unroll
    for (int r = 0; r < 4; ++r)
        outp[(long long)(bm + quad * 4 + r) * 1024 + g * 64 + o] = oacc[r] + bc;
}

// Merged both directions: z<16 -> gt (g=z, 32 row-blocks), z>=16 -> ctx.
__global__ __launch_bounds__(256) void attn_out_kernel(
    const unsigned short* __restrict__ qk,
    const _Float16* __restrict__ bias_gt, const _Float16* __restrict__ bias_ctx,
    const unsigned short* __restrict__ vt, const float* __restrict__ b_conv,
    float* __restrict__ out_gt, float* __restrict__ out_ctx)
{
    __shared__ __align__(16) unsigned short tile[64 * 72];
    __shared__ __align__(16) unsigned short wpack[16 * 1032];
    __shared__ float redA[64], redB[64];

    const int z = blockIdx.z;
    if (z < 16) {
        if (blockIdx.x >= 32) return;      // block-uniform exit
        attn_body<16>(z, blockIdx.x, qk, qk + 524288LL, bias_gt, vt, 512,
                      b_conv, out_gt, tile, wpack, redA, redB);
    } else {
        attn_body<8>(z - 16, blockIdx.x, qk + 524288LL, qk, bias_ctx, vt, 0,
                     b_conv, out_ctx, tile, wpack, redA, redB);
    }
}

// ---------------------------------------------------------------------------
__global__ __launch_bounds__(256) void conv5_f32_bf16(
    const float* s0, unsigned short* d0, int n0,
    const float* s1, unsigned short* d1, int n1,
    const float* s2, unsigned short* d2, int n2,
    const float* s3, unsigned short* d3, int n3,
    const float* s4, unsigned short* d4, int n4)
{
    const float* s; unsigned short* d; int n;
    switch (blockIdx.y) {
        case 0: s = s0; d = d0; n = n0; break;
        case 1: s = s1; d = d1; n = n1; break;
        case 2: s = s2; d = d2; n = n2; break;
        case 3: s = s3; d = d3; n = n3; break;
        default: s = s4; d = d4; n = n4; break;
    }
    int idx = (blockIdx.x * 256 + threadIdx.x) * 4;
    if (idx < n) {
        float4 v = *(const float4*)(s + idx);
        ushort4 o;
        o.x = f32_bf16_rne(v.x); o.y = f32_bf16_rne(v.y);
        o.z = f32_bf16_rne(v.z); o.w = f32_bf16_rne(v.w);
        *(ushort4*)(d + idx) = o;
    }
}

// ---------------------------------------------------------------------------
extern "C" void kernel_launch(void* const* d_in, const int* in_sizes, int n_in,
                              void* d_out, int out_size, void* d_ws, size_t ws_size,
                              hipStream_t stream)
{
    const float* feat     = (const float*)d_in[0];
    const float* ctx_feat = (const float*)d_in[1];
    const float* box      = (const float*)d_in[2];
    const float* ctx_box  = (const float*)d_in[3];
    const float* w_fc_gt  = (const float*)d_in[4];
    const float* b_fc_gt  = (const float*)d_in[5];
    const float* w_fc_ctx = (const float*)d_in[6];
    const float* b_fc_ctx = (const float*)d_in[7];
    const float* w_pos_gt = (const float*)d_in[8];
    const float* b_pos_gt = (const float*)d_in[9];
    const float* w_pos_ctx= (const float*)d_in[10];
    const float* b_pos_ctx= (const float*)d_in[11];
    const float* w_conv   = (const float*)d_in[12];
    const float* b_conv   = (const float*)d_in[13];

    float* ws = (float*)d_ws;
    unsigned short* in_bf   = (unsigned short*)ws;           // 1572864 s
    unsigned short* ctx_bf  = in_bf + 524288LL;
    unsigned short* qk_bf   = in_bf + 1572864LL;             // 1572864 s
    _Float16* bias_gt  = (_Float16*)(ws + 1572864LL);        // 8388608 h
    _Float16* bias_ctx = (_Float16*)(ws + 5767168LL);        // 8388608 h
    unsigned short* wconv_bf = (unsigned short*)(ws + 9961472LL);   // 1048576 s
    unsigned short* vt_bf    = (unsigned short*)(ws + 10485760LL);  // 1572864 s
    unsigned short* wfcgt_bf = (unsigned short*)(ws + 11272192LL);  // 1048576 s
    unsigned short* wfcctx_bf= wfcgt_bf + 1048576LL;                // 1048576 s

    float* out_gt  = (float*)d_out;
    float* out_ctx = (float*)d_out + 524288LL;

    // 1) casts
    hipLaunchKernelGGL(conv5_f32_bf16, dim3(1024, 5), dim3(256), 0, stream,
                       feat, in_bf, 524288,
                       ctx_feat, ctx_bf, 1048576,
                       w_fc_gt, wfcgt_bf, 1048576,
                       w_fc_ctx, wfcctx_bf, 1048576,
                       w_conv, wconv_bf, 1048576);

    // 2) position bias (fp16) via hi/lo-split MFMA
    hipLaunchKernelGGL(pos_bias_kernel, dim3(8192, 1, 2), dim3(256), 0, stream,
                       box, ctx_box, w_pos_gt, b_pos_gt, w_pos_ctx, b_pos_ctx,
                       bias_gt, bias_ctx);

    // 3) merged q/k projection + v-projection
    hipLaunchKernelGGL(projvt_kernel, dim3(24, 16, 2), dim3(256), 0, stream,
                       in_bf, wfcgt_bf, wfcctx_bf, b_fc_gt, b_fc_ctx, qk_bf,
                       wconv_bf, vt_bf);

    // 4) fused scores+softmax+output, both directions
    hipLaunchKernelGGL(attn_out_kernel, dim3(64, 1, 32), dim3(256), 0, stream,
                       qk_bf, bias_gt, bias_ctx, vt_bf, b_conv, out_gt, out_ctx);
}